// Round 5
// baseline (168.674 us; speedup 1.0000x reference)
//
#include <hip/hip_runtime.h>
#include <math.h>
#include <stdint.h>

#define NQ 10
#define DEPTH 6

typedef _Float16 f16x8 __attribute__((ext_vector_type(8)));
typedef float f32x4 __attribute__((ext_vector_type(4)));

typedef __attribute__((address_space(3))) unsigned int lds_u32;
typedef const __attribute__((address_space(1))) unsigned int glb_u32;

__device__ __forceinline__ void async_load16(const unsigned short* g, unsigned short* l) {
    __builtin_amdgcn_global_load_lds((glb_u32*)g, (lds_u32*)l, 16, 0, 0);
}

// ---------------------------------------------------------------------------
// lane_xor<M>: bitwise-identical replacement for __shfl_xor(v, M, 64).
// M=1,2  -> DPP quad_perm (pure VALU, no LDS pipe)
// M=4,8,16 -> ds_swizzle immediate (no bpermute addr setup)
// M=32   -> __shfl_xor (crosses 32-lane halves; swizzle can't)
// ---------------------------------------------------------------------------
template <int M>
__device__ __forceinline__ float lane_xor(float v) {
    if constexpr (M == 1) {
        int r = __builtin_amdgcn_update_dpp(
            __builtin_bit_cast(int, v), __builtin_bit_cast(int, v),
            0xB1, 0xF, 0xF, false);                       // quad_perm [1,0,3,2]
        return __builtin_bit_cast(float, r);
    } else if constexpr (M == 2) {
        int r = __builtin_amdgcn_update_dpp(
            __builtin_bit_cast(int, v), __builtin_bit_cast(int, v),
            0x4E, 0xF, 0xF, false);                       // quad_perm [2,3,0,1]
        return __builtin_bit_cast(float, r);
    } else if constexpr (M == 4) {
        return __builtin_bit_cast(float,
            __builtin_amdgcn_ds_swizzle(__builtin_bit_cast(int, v), 0x101F));
    } else if constexpr (M == 8) {
        return __builtin_bit_cast(float,
            __builtin_amdgcn_ds_swizzle(__builtin_bit_cast(int, v), 0x201F));
    } else if constexpr (M == 16) {
        return __builtin_bit_cast(float,
            __builtin_amdgcn_ds_swizzle(__builtin_bit_cast(int, v), 0x401F));
    } else {
        return __shfl_xor(v, 32, 64);
    }
}

// ---------------------------------------------------------------------------
// Gate precompute: Rot = RZ(omega) RY(theta) RZ(phi)
// ---------------------------------------------------------------------------
__device__ __forceinline__ void compute_gate(const float* __restrict__ weights,
                                             int idx, float* __restrict__ g) {
    float phi   = weights[idx * 3 + 0];
    float theta = weights[idx * 3 + 1];
    float omega = weights[idx * 3 + 2];
    float c = cosf(0.5f * theta), s = sinf(0.5f * theta);
    float ap = -0.5f * (phi + omega);
    float am = -0.5f * (phi - omega);
    float epr = cosf(ap), epi = sinf(ap);
    float emr = cosf(am), emi = sinf(am);
    g[0] =  epr * c;  g[1] =  epi * c;
    g[2] = -emr * s;  g[3] =  emi * s;
    g[4] =  emr * s;  g[5] =  emi * s;
    g[6] =  epr * c;  g[7] = -epi * c;
}

__global__ void prep_gates_kernel(const float* __restrict__ weights,
                                  float* __restrict__ gmat) {
    int idx = blockIdx.x * blockDim.x + threadIdx.x;
    if (idx >= DEPTH * NQ) return;
    compute_gate(weights, idx, gmat + idx * 8);
}

// ---------------------------------------------------------------------------
// Templated circuit core (hot path, transposed only). Bit-identical data
// movement to the verified generic version; shuffles via lane_xor<M>.
// amp index: bits 0..3 slot, 4..9 lane.
// ---------------------------------------------------------------------------
template <int Q>
__device__ __forceinline__ void rotT_gate(float (&ar)[16], float (&ai)[16], int lane,
                                          const float* __restrict__ g) {
    float u00r = g[0], u00i = g[1];
    float u01r = g[4], u01i = g[5];   // transposed: u01 = orig u10
    float u10r = g[2], u10i = g[3];   // transposed: u10 = orig u01
    float u11r = g[6], u11i = g[7];
    if constexpr (Q < 4) {
#pragma unroll
        for (int j = 0; j < 16; ++j) {
            if ((j >> Q) & 1) continue;
            int j1 = j | (1 << Q);
            float a0r = ar[j],  a0i = ai[j];
            float a1r = ar[j1], a1i = ai[j1];
            ar[j]  = u00r*a0r - u00i*a0i + u01r*a1r - u01i*a1i;
            ai[j]  = u00r*a0i + u00i*a0r + u01r*a1i + u01i*a1r;
            ar[j1] = u10r*a0r - u10i*a0i + u11r*a1r - u11i*a1i;
            ai[j1] = u10r*a0i + u10i*a0r + u11r*a1i + u11i*a1r;
        }
    } else {
        constexpr int M = 1 << (Q - 4);
        bool hi = (lane >> (Q - 4)) & 1;
        float car = hi ? u11r : u00r, cai = hi ? u11i : u00i;
        float cbr = hi ? u10r : u01r, cbi = hi ? u10i : u01i;
        float pr[16], pi[16];
#pragma unroll
        for (int j = 0; j < 16; ++j) pr[j] = lane_xor<M>(ar[j]);
#pragma unroll
        for (int j = 0; j < 16; ++j) pi[j] = lane_xor<M>(ai[j]);
#pragma unroll
        for (int j = 0; j < 16; ++j) {
            float mr = ar[j], mi = ai[j];
            ar[j] = car*mr - cai*mi + cbr*pr[j] - cbi*pi[j];
            ai[j] = car*mi + cai*mr + cbr*pi[j] + cbi*pr[j];
        }
    }
}

// shared (non-templated) transposed rot layer — keeps code size down;
// gate qubit index stays compile-time via rotT_gate<Q>.
__device__ __forceinline__ void rotT_layer(float (&ar)[16], float (&ai)[16], int lane,
                                           const float* __restrict__ gl) {
    rotT_gate<0>(ar, ai, lane, gl + 0);
    rotT_gate<1>(ar, ai, lane, gl + 8);
    rotT_gate<2>(ar, ai, lane, gl + 16);
    rotT_gate<3>(ar, ai, lane, gl + 24);
    rotT_gate<4>(ar, ai, lane, gl + 32);
    rotT_gate<5>(ar, ai, lane, gl + 40);
    rotT_gate<6>(ar, ai, lane, gl + 48);
    rotT_gate<7>(ar, ai, lane, gl + 56);
    rotT_gate<8>(ar, ai, lane, gl + 64);
    rotT_gate<9>(ar, ai, lane, gl + 72);
}

template <int C, int T>
__device__ __forceinline__ void cnot_t(float (&ar)[16], float (&ai)[16], int lane) {
    if constexpr (C < 4 && T < 4) {
#pragma unroll
        for (int j = 0; j < 16; ++j) {
            if (((j >> C) & 1) && !((j >> T) & 1)) {
                int j1 = j | (1 << T);
                float tr = ar[j]; ar[j] = ar[j1]; ar[j1] = tr;
                float ti = ai[j]; ai[j] = ai[j1]; ai[j1] = ti;
            }
        }
    } else if constexpr (C < 4) {
        constexpr int M = 1 << (T - 4);
        float pr[16], pi[16];
#pragma unroll
        for (int j = 0; j < 16; ++j)
            if ((j >> C) & 1) pr[j] = lane_xor<M>(ar[j]);
#pragma unroll
        for (int j = 0; j < 16; ++j)
            if ((j >> C) & 1) pi[j] = lane_xor<M>(ai[j]);
#pragma unroll
        for (int j = 0; j < 16; ++j)
            if ((j >> C) & 1) { ar[j] = pr[j]; ai[j] = pi[j]; }
    } else if constexpr (T < 4) {
        bool cb = (lane >> (C - 4)) & 1;
#pragma unroll
        for (int j = 0; j < 16; ++j) {
            if (!((j >> T) & 1)) {
                int j1 = j | (1 << T);
                float lr = ar[j], li = ai[j], hr = ar[j1], hi2 = ai[j1];
                ar[j]  = cb ? hr : lr;  ai[j]  = cb ? hi2 : li;
                ar[j1] = cb ? lr : hr;  ai[j1] = cb ? li : hi2;
            }
        }
    } else {
        constexpr int M = 1 << (T - 4);
        bool cb = (lane >> (C - 4)) & 1;
        float pr[16], pi[16];
#pragma unroll
        for (int j = 0; j < 16; ++j) pr[j] = lane_xor<M>(ar[j]);
#pragma unroll
        for (int j = 0; j < 16; ++j) pi[j] = lane_xor<M>(ai[j]);
#pragma unroll
        for (int j = 0; j < 16; ++j) {
            ar[j] = cb ? pr[j] : ar[j];
            ai[j] = cb ? pi[j] : ai[j];
        }
    }
}

template <int R, int I>
__device__ __forceinline__ void cnot_ring_rev_t(float (&ar)[16], float (&ai)[16], int lane) {
    cnot_t<I, (I + R) % NQ>(ar, ai, lane);
    if constexpr (I > 0) cnot_ring_rev_t<R, I - 1>(ar, ai, lane);
}

// transposed circuit (verified round 8 structure): wave computes row g of U.
// Runtime layer loop + switch (round-2-verified shape) to bound code size.
__device__ __forceinline__ void run_circuit_T(float (&ar)[16], float (&ai)[16],
                                              const float* __restrict__ gmat, int lane) {
    for (int l = DEPTH - 1; l >= 0; --l) {
        switch (l) {
            case 0: cnot_ring_rev_t<1, NQ - 1>(ar, ai, lane); break;
            case 1: cnot_ring_rev_t<2, NQ - 1>(ar, ai, lane); break;
            case 2: cnot_ring_rev_t<3, NQ - 1>(ar, ai, lane); break;
            case 3: cnot_ring_rev_t<4, NQ - 1>(ar, ai, lane); break;
            case 4: cnot_ring_rev_t<5, NQ - 1>(ar, ai, lane); break;
            default: cnot_ring_rev_t<6, NQ - 1>(ar, ai, lane); break;
        }
        rotT_layer(ar, ai, lane, gmat + l * (NQ * 8));
    }
}

__device__ __forceinline__ float wave_sum(float v) {
    v += lane_xor<1>(v);
    v += lane_xor<2>(v);
    v += lane_xor<4>(v);
    v += lane_xor<8>(v);
    v += lane_xor<16>(v);
    v += lane_xor<32>(v);
    return v;
}

// ---------------------------------------------------------------------------
// Generic (runtime-q) circuit helpers: used only by the vqc fallback.
// ---------------------------------------------------------------------------
__device__ __forceinline__ void apply_1q_local(
    float (&ar)[16], float (&ai)[16], int q,
    float u00r, float u00i, float u01r, float u01i,
    float u10r, float u10i, float u11r, float u11i) {
#pragma unroll
    for (int j = 0; j < 16; ++j) {
        if ((j >> q) & 1) continue;
        int j1 = j | (1 << q);
        float a0r = ar[j],  a0i = ai[j];
        float a1r = ar[j1], a1i = ai[j1];
        ar[j]  = u00r*a0r - u00i*a0i + u01r*a1r - u01i*a1i;
        ai[j]  = u00r*a0i + u00i*a0r + u01r*a1i + u01i*a1r;
        ar[j1] = u10r*a0r - u10i*a0i + u11r*a1r - u11i*a1i;
        ai[j1] = u10r*a0i + u10i*a0r + u11r*a1i + u11i*a1r;
    }
}

__device__ __forceinline__ void apply_1q_lane(
    float (&ar)[16], float (&ai)[16], int q, int lane,
    float u00r, float u00i, float u01r, float u01i,
    float u10r, float u10i, float u11r, float u11i) {
    int  m  = 1 << (q - 4);
    bool hi = (lane >> (q - 4)) & 1;
    float car = hi ? u11r : u00r, cai = hi ? u11i : u00i;
    float cbr = hi ? u10r : u01r, cbi = hi ? u10i : u01i;
    float pr[16], pi[16];
#pragma unroll
    for (int j = 0; j < 16; ++j) pr[j] = __shfl_xor(ar[j], m, 64);
#pragma unroll
    for (int j = 0; j < 16; ++j) pi[j] = __shfl_xor(ai[j], m, 64);
#pragma unroll
    for (int j = 0; j < 16; ++j) {
        float mr = ar[j], mi = ai[j];
        ar[j] = car*mr - cai*mi + cbr*pr[j] - cbi*pi[j];
        ai[j] = car*mi + cai*mr + cbr*pi[j] + cbi*pr[j];
    }
}

__device__ __forceinline__ void cnot_gate(
    float (&ar)[16], float (&ai)[16], int c, int t, int lane) {
    if (c < 4 && t < 4) {
#pragma unroll
        for (int j = 0; j < 16; ++j) {
            if (((j >> c) & 1) && !((j >> t) & 1)) {
                int j1 = j | (1 << t);
                float tr = ar[j]; ar[j] = ar[j1]; ar[j1] = tr;
                float ti = ai[j]; ai[j] = ai[j1]; ai[j1] = ti;
            }
        }
    } else if (c < 4) {
        int m = 1 << (t - 4);
        float pr[16], pi[16];
#pragma unroll
        for (int j = 0; j < 16; ++j)
            if ((j >> c) & 1) pr[j] = __shfl_xor(ar[j], m, 64);
#pragma unroll
        for (int j = 0; j < 16; ++j)
            if ((j >> c) & 1) pi[j] = __shfl_xor(ai[j], m, 64);
#pragma unroll
        for (int j = 0; j < 16; ++j)
            if ((j >> c) & 1) { ar[j] = pr[j]; ai[j] = pi[j]; }
    } else if (t < 4) {
        bool cb = (lane >> (c - 4)) & 1;
#pragma unroll
        for (int j = 0; j < 16; ++j) {
            if (!((j >> t) & 1)) {
                int j1 = j | (1 << t);
                float lr = ar[j], li = ai[j], hr = ar[j1], hi2 = ai[j1];
                ar[j]  = cb ? hr : lr;  ai[j]  = cb ? hi2 : li;
                ar[j1] = cb ? lr : hr;  ai[j1] = cb ? li : hi2;
            }
        }
    } else {
        int  m  = 1 << (t - 4);
        bool cb = (lane >> (c - 4)) & 1;
        float pr[16], pi[16];
#pragma unroll
        for (int j = 0; j < 16; ++j) pr[j] = __shfl_xor(ar[j], m, 64);
#pragma unroll
        for (int j = 0; j < 16; ++j) pi[j] = __shfl_xor(ai[j], m, 64);
#pragma unroll
        for (int j = 0; j < 16; ++j) {
            ar[j] = cb ? pr[j] : ar[j];
            ai[j] = cb ? pi[j] : ai[j];
        }
    }
}

template <int R>
__device__ __forceinline__ void cnot_ring(float (&ar)[16], float (&ai)[16], int lane) {
#pragma unroll
    for (int i = 0; i < NQ; ++i) cnot_gate(ar, ai, i, (i + R) % NQ, lane);
}

// forward circuit (fallback vqc_kernel)
__device__ __forceinline__ void run_circuit(float (&ar)[16], float (&ai)[16],
                                            const float* __restrict__ gmat, int lane) {
    for (int l = 0; l < DEPTH; ++l) {
        const float* gl = gmat + l * (NQ * 8);
#pragma unroll
        for (int i = 0; i < NQ; ++i) {
            const float* g = gl + i * 8;
            float u00r = g[0], u00i = g[1], u01r = g[2], u01i = g[3];
            float u10r = g[4], u10i = g[5], u11r = g[6], u11i = g[7];
            if (i < 4)
                apply_1q_local(ar, ai, i, u00r,u00i,u01r,u01i,u10r,u10i,u11r,u11i);
            else
                apply_1q_lane(ar, ai, i, lane, u00r,u00i,u01r,u01i,u10r,u10i,u11r,u11i);
        }
        switch (l) {
            case 0: cnot_ring<1>(ar, ai, lane); break;
            case 1: cnot_ring<2>(ar, ai, lane); break;
            case 2: cnot_ring<3>(ar, ai, lane); break;
            case 3: cnot_ring<4>(ar, ai, lane); break;
            case 4: cnot_ring<5>(ar, ai, lane); break;
            default: cnot_ring<6>(ar, ai, lane); break;
        }
    }
}

// ---------------------------------------------------------------------------
// proj body: float4 loads (verified round 10) + fast trig (verified r4).
// ---------------------------------------------------------------------------
__device__ __forceinline__ void proj_v_body(
    const float* __restrict__ x, const float* __restrict__ Wproj,
    _Float16* __restrict__ V, int b, int lane) {
    const float4* xb4 = (const float4*)(x + (size_t)b * 1024);
    const float4* W4  = (const float4*)Wproj;        // [q][256]
    float acc[NQ];
#pragma unroll
    for (int q = 0; q < NQ; ++q) acc[q] = 0.f;
#pragma unroll
    for (int k4 = 0; k4 < 4; ++k4) {
        float4 xv = xb4[k4 * 64 + lane];
#pragma unroll
        for (int q = 0; q < NQ; ++q) {
            float4 wv = W4[q * 256 + k4 * 64 + lane];
            acc[q] = fmaf(xv.x, wv.x, acc[q]);
            acc[q] = fmaf(xv.y, wv.y, acc[q]);
            acc[q] = fmaf(xv.z, wv.z, acc[q]);
            acc[q] = fmaf(xv.w, wv.w, acc[q]);
        }
    }
#pragma unroll
    for (int q = 0; q < NQ; ++q) acc[q] = wave_sum(acc[q]);

    float cq[NQ], sq[NQ];
#pragma unroll
    for (int q = 0; q < NQ; ++q) {
        float e  = __expf(2.f * acc[q]);
        float th = 1.f - __fdividef(2.f, e + 1.f);       // tanh(acc)
        float ha = th * 0.785398163397448310f;            // 0.5 * ang
        cq[q] = __cosf(ha);
        sq[q] = __sinf(ha);
    }
    float laneprod = 1.f;
#pragma unroll
    for (int q = 4; q < NQ; ++q)
        laneprod *= ((lane >> (q - 4)) & 1) ? sq[q] : cq[q];

    unsigned int buf[8];
#pragma unroll
    for (int jj = 0; jj < 8; ++jj) {
        unsigned short h2[2];
#pragma unroll
        for (int c = 0; c < 2; ++c) {
            int j = jj * 2 + c;
            float p = laneprod;
#pragma unroll
            for (int q = 0; q < 4; ++q) p *= ((j >> q) & 1) ? sq[q] : cq[q];
            h2[c] = __builtin_bit_cast(unsigned short, (_Float16)p);
        }
        buf[jj] = (unsigned int)h2[0] | ((unsigned int)h2[1] << 16);
    }
    uint4* dst = (uint4*)(V + (size_t)b * 1024 + 16 * lane);
    uint4 v0; v0.x = buf[0]; v0.y = buf[1]; v0.z = buf[2]; v0.w = buf[3];
    uint4 v1; v1.x = buf[4]; v1.y = buf[5]; v1.z = buf[6]; v1.w = buf[7];
    dst[0] = v0; dst[1] = v1;
}

// ---------------------------------------------------------------------------
// Kernel A (round 5: 512-thread blocks for circuit TLP):
//   blocks [0,128): 8 waves = 8 basis columns each -> 2 circuit waves/SIMD
//                   guaranteed co-resident (latency hiding for the serial
//                   gate chain). Also zeroes `out` for the gemm atomics.
//   blocks [128, 128+B/8): projection, 8 rows per block.
// ---------------------------------------------------------------------------
__global__ __launch_bounds__(512) void basis_proj_kernel(
    const float* __restrict__ weights, _Float16* __restrict__ Bt,
    const float* __restrict__ x, const float* __restrict__ Wproj,
    _Float16* __restrict__ V, float* __restrict__ out, int B) {
    __shared__ float gmat_s[DEPTH * NQ * 8];
    int tid  = threadIdx.x;
    int lane = tid & 63;
    int w    = tid >> 6;                 // 0..7

    if (blockIdx.x < 128) {
        // zero the output accumulator (gemm atomically adds into it)
        for (int i = blockIdx.x * 512 + tid; i < B * NQ; i += 128 * 512)
            out[i] = 0.f;
        if (tid < DEPTH * NQ) compute_gate(weights, tid, gmat_s + tid * 8);
        __syncthreads();

        int g = blockIdx.x * 8 + w;          // basis index = output row pair
        float ar[16], ai[16];
#pragma unroll
        for (int jj = 0; jj < 16; ++jj) {
            ar[jj] = (lane == (g >> 4) && jj == (g & 15)) ? 1.f : 0.f;
            ai[jj] = 0.f;
        }
        run_circuit_T(ar, ai, gmat_s, lane);

        unsigned int bufr[8], bufi[8];
#pragma unroll
        for (int jj = 0; jj < 8; ++jj) {
            unsigned short r0 = __builtin_bit_cast(unsigned short, (_Float16)ar[2*jj]);
            unsigned short r1 = __builtin_bit_cast(unsigned short, (_Float16)ar[2*jj+1]);
            unsigned short i0 = __builtin_bit_cast(unsigned short, (_Float16)ai[2*jj]);
            unsigned short i1 = __builtin_bit_cast(unsigned short, (_Float16)ai[2*jj+1]);
            bufr[jj] = (unsigned int)r0 | ((unsigned int)r1 << 16);
            bufi[jj] = (unsigned int)i0 | ((unsigned int)i1 << 16);
        }
        uint4* dre = (uint4*)((unsigned short*)Bt + (size_t)(2*g)     * 1024 + 16 * lane);
        uint4* dim = (uint4*)((unsigned short*)Bt + (size_t)(2*g + 1) * 1024 + 16 * lane);
        uint4 v;
        v.x = bufr[0]; v.y = bufr[1]; v.z = bufr[2]; v.w = bufr[3]; dre[0] = v;
        v.x = bufr[4]; v.y = bufr[5]; v.z = bufr[6]; v.w = bufr[7]; dre[1] = v;
        v.x = bufi[0]; v.y = bufi[1]; v.z = bufi[2]; v.w = bufi[3]; dim[0] = v;
        v.x = bufi[4]; v.y = bufi[5]; v.z = bufi[6]; v.w = bufi[7]; dim[1] = v;
    } else {
        int b = (int)(blockIdx.x - 128) * 8 + w;
        if (b < B) proj_v_body(x, Wproj, V, b, lane);
    }
}

// ---------------------------------------------------------------------------
// Kernel B: fused GEMM + |psi|^2 + partial-Z reduction + head fold.
// K-loop unchanged (round-2 verified phase pipeline: BK=32, quad-buffered
// LDS, 3 tiles ahead, counted vmcnt(8)). Epilogue butterfly unchanged.
// NEW (round 5): the per-tile partials are a signed LINEAR function of the
// final head output, so each block folds Wout/bias directly and atomicAdds
// into out — combine_head kernel eliminated.
//   Zq[0..5] additive over nb; Zq[6+k] = sum_nb (-1)^{bit_k(nb)} T_nb.
// ---------------------------------------------------------------------------
#define STG(dst_, src_, kt_) do {                                                   \
    _Pragma("unroll")                                                               \
    for (int s_ = 0; s_ < 2; ++s_) {                                                \
        async_load16(src_ + (size_t)(s_ * 128 + srow) * 1024 + (kt_) * 32 + scg * 8,\
                     dst_ + s_ * 4096 + w * 512);                                   \
    }                                                                               \
} while (0)

__global__ __launch_bounds__(512, 2) void gemm_fused_kernel(
    const unsigned short* __restrict__ A,    // V (B,1024)
    const unsigned short* __restrict__ Bt,   // (2048,1024)
    const float* __restrict__ Wout,          // (10,10)
    const float* __restrict__ bout,          // (10)
    float* __restrict__ out) {               // (B,10) pre-zeroed
    __shared__ __align__(16) unsigned short lds_s[4 * 16384];  // 128 KiB
    int tid  = threadIdx.x;
    int lane = tid & 63;
    int w    = tid >> 6;                 // 0..7
    int wm   = w >> 2;                   // 0..1 : 128-row half
    int wn   = w & 3;                    // 0..3 : 64-col quarter
    int by   = blockIdx.x & 7;           // XCD id -> Bt panel (L2 locality)
    int bx   = blockIdx.x >> 3;
    int m0   = bx * 256;
    int n0   = by * 256;
    int quad = lane >> 4;
    int lrow = lane & 15;
    int csw  = (quad ^ ((lrow >> 1) & 3)) * 8;   // swizzled read-chunk offset (shorts)
    int srow = tid >> 2;                          // staging row within 128-row sweep
    int scg  = (tid & 3) ^ ((srow >> 1) & 3);     // swizzled source chunk
    const unsigned short* Abase = A  + (size_t)m0 * 1024;
    const unsigned short* Bbase = Bt + (size_t)n0 * 1024;

    f32x4 acc[8][4];
#pragma unroll
    for (int mi = 0; mi < 8; ++mi)
#pragma unroll
        for (int ni = 0; ni < 4; ++ni)
            acc[mi][ni] = (f32x4){0.f, 0.f, 0.f, 0.f};

    // prologue: stage tiles 0,1,2 (12 loads); validate tile 0
    STG(lds_s + 0 * 16384,        Abase, 0);
    STG(lds_s + 0 * 16384 + 8192, Bbase, 0);
    STG(lds_s + 1 * 16384,        Abase, 1);
    STG(lds_s + 1 * 16384 + 8192, Bbase, 1);
    STG(lds_s + 2 * 16384,        Abase, 2);
    STG(lds_s + 2 * 16384 + 8192, Bbase, 2);
    asm volatile("s_waitcnt vmcnt(8)" ::: "memory");
    __builtin_amdgcn_s_barrier();

    int rowA = wm * 128 + lrow;          // + mi*16
    int rowB = wn * 64  + lrow;          // + ni*16

    for (int t = 0; t < 32; ++t) {
        const unsigned short* bufA = lds_s + (t & 3) * 16384;
        const unsigned short* bufB = bufA + 8192;
        unsigned short* nbuf = lds_s + ((t + 3) & 3) * 16384;
        f16x8 af[4], bf[4];
        // ---------------- phase 0: mi 0..3 ----------------
#pragma unroll
        for (int i = 0; i < 4; ++i)
            af[i] = *(const f16x8*)(bufA + (rowA + i * 16) * 32 + csw);
#pragma unroll
        for (int i = 0; i < 4; ++i)
            bf[i] = *(const f16x8*)(bufB + (rowB + i * 16) * 32 + csw);
        if (t < 29) STG(nbuf, Abase, t + 3);
        __builtin_amdgcn_s_barrier();
        asm volatile("s_waitcnt lgkmcnt(0)" ::: "memory");
        __builtin_amdgcn_sched_barrier(0);
        __builtin_amdgcn_s_setprio(1);
#pragma unroll
        for (int mi = 0; mi < 4; ++mi)
#pragma unroll
            for (int ni = 0; ni < 4; ++ni)
                acc[mi][ni] = __builtin_amdgcn_mfma_f32_16x16x32_f16(
                    af[mi], bf[ni], acc[mi][ni], 0, 0, 0);
        __builtin_amdgcn_s_setprio(0);
        __builtin_amdgcn_s_barrier();
        // ---------------- phase 1: mi 4..7 ----------------
#pragma unroll
        for (int i = 0; i < 4; ++i)
            af[i] = *(const f16x8*)(bufA + (rowA + 64 + i * 16) * 32 + csw);
        if (t < 29) {
            STG(nbuf + 8192, Bbase, t + 3);
            asm volatile("s_waitcnt vmcnt(8)" ::: "memory");   // validate t+1
        } else {
            asm volatile("s_waitcnt vmcnt(0)" ::: "memory");   // 3-tile tail drain
        }
        __builtin_amdgcn_s_barrier();
        asm volatile("s_waitcnt lgkmcnt(0)" ::: "memory");
        __builtin_amdgcn_sched_barrier(0);
        __builtin_amdgcn_s_setprio(1);
#pragma unroll
        for (int mi = 0; mi < 4; ++mi)
#pragma unroll
            for (int ni = 0; ni < 4; ++ni)
                acc[mi + 4][ni] = __builtin_amdgcn_mfma_f32_16x16x32_f16(
                    af[mi], bf[ni], acc[mi + 4][ni], 0, 0, 0);
        __builtin_amdgcn_s_setprio(0);
        __builtin_amdgcn_s_barrier();
    }

    // ---- epilogue: square + signed reduce (stride-9 LDS, conflict-free) ----
    float* Zs = (float*)lds_s;                 // [2 nb][2 half][256 rows][9]
    int nbl  = wn >> 1;
    int half = wn & 1;
#pragma unroll
    for (int mi = 0; mi < 8; ++mi) {
#pragma unroll
        for (int r = 0; r < 4; ++r) {
            float p0 = acc[mi][0][r] * acc[mi][0][r];
            float p1 = acc[mi][1][r] * acc[mi][1][r];
            float p2 = acc[mi][2][r] * acc[mi][2][r];
            float p3 = acc[mi][3][r] * acc[mi][3][r];
            float t0 = (p0 + p1) + (p2 + p3);
            float t3 = (p0 - p1) + (p2 - p3);
            float t4 = (p0 + p1) - (p2 + p3);
            t0 += lane_xor<1>(t0);
            t3 += lane_xor<1>(t3);
            t4 += lane_xor<1>(t4);
            float u2 = lane_xor<2>(t0);
            float ap = t0 + u2;
            float am = (lane & 2) ? u2 - t0 : t0 - u2;
            t3 += lane_xor<2>(t3);
            t4 += lane_xor<2>(t4);
            float u4  = lane_xor<4>(ap);
            float bpp = ap + u4;
            float bpm = (lane & 4) ? u4 - ap : ap - u4;
            float bmp = am + lane_xor<4>(am);
            t3 += lane_xor<4>(t3);
            t4 += lane_xor<4>(t4);
            float u8 = lane_xor<8>(bpp);
            float T  = bpp + u8;
            float Z2 = (lane & 8) ? u8 - bpp : bpp - u8;
            float Z1 = bpm + lane_xor<8>(bpm);
            float Z0 = bmp + lane_xor<8>(bmp);
            t3 += lane_xor<8>(t3);
            t4 += lane_xor<8>(t4);
            if (lrow == 0) {
                int row = wm * 128 + mi * 16 + quad * 4 + r;
                float* z = Zs + ((size_t)(nbl * 2 + half) * 256 + row) * 9;
                z[0] = T;  z[1] = Z0; z[2] = Z1; z[3] = Z2;
                z[4] = t3; z[5] = t4;
            }
        }
    }
    __syncthreads();
    if (tid < 256) {
        int row = tid;
        float contrib[NQ];
#pragma unroll
        for (int q = 0; q < NQ; ++q) contrib[q] = 0.f;
#pragma unroll
        for (int nbl2 = 0; nbl2 < 2; ++nbl2) {
            const float* za = Zs + ((size_t)(nbl2 * 2 + 0) * 256 + row) * 9;
            const float* zb = Zs + ((size_t)(nbl2 * 2 + 1) * 256 + row) * 9;
            float Ta = za[0], Tb = zb[0];
            contrib[0] += za[1] + zb[1];          // Z0
            contrib[1] += za[2] + zb[2];          // Z1
            contrib[2] += za[3] + zb[3];          // Z2
            contrib[3] += za[4] + zb[4];          // Z3
            contrib[4] += za[5] + zb[5];          // Z4
            contrib[5] += Ta - Tb;                // Z5 (half split)
            float Tnb = Ta + Tb;
            int nb = by * 2 + nbl2;               // global n-tile index 0..15
            contrib[6] += (nb & 1) ? -Tnb : Tnb;  // Z6: sign bit0
            contrib[7] += (nb & 2) ? -Tnb : Tnb;  // Z7: sign bit1
            contrib[8] += (nb & 4) ? -Tnb : Tnb;  // Z8: sign bit2
            contrib[9] += (nb & 8) ? -Tnb : Tnb;  // Z9: sign bit3
        }
        float* orow = out + (size_t)(m0 + row) * NQ;
#pragma unroll
        for (int c = 0; c < NQ; ++c) {
            float o = (by == 0) ? bout[c] : 0.f;  // bias added exactly once per b
#pragma unroll
            for (int q = 0; q < NQ; ++q) o = fmaf(contrib[q], Wout[c * NQ + q], o);
            atomicAdd(&orow[c], o);
        }
    }
}

// ---------------------------------------------------------------------------
// Fallback: round-1 monolithic kernel (verified).
// ---------------------------------------------------------------------------
__global__ __launch_bounds__(256) void vqc_kernel(
    const float* __restrict__ x, const float* __restrict__ Wproj,
    const float* __restrict__ gmat, const float* __restrict__ Wout,
    const float* __restrict__ bout, float* __restrict__ out, int B) {
    int lane = threadIdx.x & 63;
    int wid  = threadIdx.x >> 6;
    int b    = blockIdx.x * 4 + wid;
    if (b >= B) return;

    const float* xb = x + (size_t)b * 1024;
    float acc[NQ];
#pragma unroll
    for (int q = 0; q < NQ; ++q) acc[q] = 0.f;
#pragma unroll
    for (int k = 0; k < 16; ++k) {
        float xv = xb[k * 64 + lane];
#pragma unroll
        for (int q = 0; q < NQ; ++q)
            acc[q] = fmaf(xv, Wproj[q * 1024 + k * 64 + lane], acc[q]);
    }
#pragma unroll
    for (int q = 0; q < NQ; ++q) acc[q] = wave_sum(acc[q]);

    float cq[NQ], sq[NQ];
#pragma unroll
    for (int q = 0; q < NQ; ++q) {
        float ang = tanhf(acc[q]) * 1.57079632679489662f;
        cq[q] = cosf(0.5f * ang);
        sq[q] = sinf(0.5f * ang);
    }
    float laneprod = 1.f;
#pragma unroll
    for (int q = 4; q < NQ; ++q)
        laneprod *= ((lane >> (q - 4)) & 1) ? sq[q] : cq[q];
    float ar[16], ai[16];
#pragma unroll
    for (int j = 0; j < 16; ++j) {
        float p = laneprod;
#pragma unroll
        for (int q = 0; q < 4; ++q) p *= ((j >> q) & 1) ? sq[q] : cq[q];
        ar[j] = p; ai[j] = 0.f;
    }
    run_circuit(ar, ai, gmat, lane);

    float T = 0.f, S[4] = {0.f, 0.f, 0.f, 0.f};
#pragma unroll
    for (int j = 0; j < 16; ++j) {
        float p = ar[j] * ar[j] + ai[j] * ai[j];
        T += p;
#pragma unroll
        for (int q = 0; q < 4; ++q) S[q] += ((j >> q) & 1) ? -p : p;
    }
    float Zq[NQ];
#pragma unroll
    for (int q = 0; q < 4; ++q) Zq[q] = S[q];
#pragma unroll
    for (int q = 4; q < NQ; ++q) Zq[q] = ((lane >> (q - 4)) & 1) ? -T : T;
#pragma unroll
    for (int q = 0; q < NQ; ++q) Zq[q] = wave_sum(Zq[q]);
    if (lane < NQ) {
        float o = bout[lane];
#pragma unroll
        for (int q = 0; q < NQ; ++q) o = fmaf(Zq[q], Wout[lane * NQ + q], o);
        out[(size_t)b * NQ + lane] = o;
    }
}

extern "C" void kernel_launch(void* const* d_in, const int* in_sizes, int n_in,
                              void* d_out, int out_size, void* d_ws, size_t ws_size,
                              hipStream_t stream) {
    const float* x       = (const float*)d_in[0];
    const float* Wproj   = (const float*)d_in[1];
    const float* weights = (const float*)d_in[2];
    const float* Wout    = (const float*)d_in[3];
    const float* bout    = (const float*)d_in[4];
    float* out = (float*)d_out;
    int B = in_sizes[0] / 1024;

    char* ws = (char*)d_ws;
    size_t off_Bt = 4096;
    size_t off_V  = off_Bt + (size_t)2048 * 1024 * 2;
    size_t need   = off_V  + (size_t)B * 1024 * 2;

    if (ws_size >= need && (B % 256) == 0) {
        _Float16* Bt = (_Float16*)(ws + off_Bt);
        _Float16* V  = (_Float16*)(ws + off_V);

        basis_proj_kernel<<<128 + B / 8, 512, 0, stream>>>(weights, Bt, x, Wproj, V, out, B);
        gemm_fused_kernel<<<(B / 256) * 8, 512, 0, stream>>>(
            (const unsigned short*)V, (const unsigned short*)Bt, Wout, bout, out);
    } else {
        float* gmat = (float*)ws;
        prep_gates_kernel<<<1, 64, 0, stream>>>(weights, gmat);
        vqc_kernel<<<(B + 3) / 4, 256, 0, stream>>>(x, Wproj, gmat, Wout, bout, out, B);
    }
}

// Round 6
// 162.190 us; speedup vs baseline: 1.0400x; 1.0400x over previous
//
#include <hip/hip_runtime.h>
#include <math.h>
#include <stdint.h>

#define NQ 10
#define DEPTH 6

typedef _Float16 f16x8 __attribute__((ext_vector_type(8)));
typedef float f32x4 __attribute__((ext_vector_type(4)));

typedef __attribute__((address_space(3))) unsigned int lds_u32;
typedef const __attribute__((address_space(1))) unsigned int glb_u32;

__device__ __forceinline__ void async_load16(const unsigned short* g, unsigned short* l) {
    __builtin_amdgcn_global_load_lds((glb_u32*)g, (lds_u32*)l, 16, 0, 0);
}

// ---------------------------------------------------------------------------
// lane_xor<M>: bitwise-identical replacement for __shfl_xor(v, M, 64).
// ---------------------------------------------------------------------------
template <int M>
__device__ __forceinline__ float lane_xor(float v) {
    if constexpr (M == 1) {
        int r = __builtin_amdgcn_update_dpp(
            __builtin_bit_cast(int, v), __builtin_bit_cast(int, v),
            0xB1, 0xF, 0xF, false);                       // quad_perm [1,0,3,2]
        return __builtin_bit_cast(float, r);
    } else if constexpr (M == 2) {
        int r = __builtin_amdgcn_update_dpp(
            __builtin_bit_cast(int, v), __builtin_bit_cast(int, v),
            0x4E, 0xF, 0xF, false);                       // quad_perm [2,3,0,1]
        return __builtin_bit_cast(float, r);
    } else if constexpr (M == 4) {
        return __builtin_bit_cast(float,
            __builtin_amdgcn_ds_swizzle(__builtin_bit_cast(int, v), 0x101F));
    } else if constexpr (M == 8) {
        return __builtin_bit_cast(float,
            __builtin_amdgcn_ds_swizzle(__builtin_bit_cast(int, v), 0x201F));
    } else if constexpr (M == 16) {
        return __builtin_bit_cast(float,
            __builtin_amdgcn_ds_swizzle(__builtin_bit_cast(int, v), 0x401F));
    } else {
        return __shfl_xor(v, 32, 64);
    }
}

// ---------------------------------------------------------------------------
// Gate precompute: Rot = RZ(omega) RY(theta) RZ(phi)
// ---------------------------------------------------------------------------
__device__ __forceinline__ void compute_gate(const float* __restrict__ weights,
                                             int idx, float* __restrict__ g) {
    float phi   = weights[idx * 3 + 0];
    float theta = weights[idx * 3 + 1];
    float omega = weights[idx * 3 + 2];
    float c = cosf(0.5f * theta), s = sinf(0.5f * theta);
    float ap = -0.5f * (phi + omega);
    float am = -0.5f * (phi - omega);
    float epr = cosf(ap), epi = sinf(ap);
    float emr = cosf(am), emi = sinf(am);
    g[0] =  epr * c;  g[1] =  epi * c;
    g[2] = -emr * s;  g[3] =  emi * s;
    g[4] =  emr * s;  g[5] =  emi * s;
    g[6] =  epr * c;  g[7] = -epi * c;
}

__global__ void prep_gates_kernel(const float* __restrict__ weights,
                                  float* __restrict__ gmat) {
    int idx = blockIdx.x * blockDim.x + threadIdx.x;
    if (idx >= DEPTH * NQ) return;
    compute_gate(weights, idx, gmat + idx * 8);
}

// ---------------------------------------------------------------------------
// Two-column interleaved transposed circuit (round 6): each wave evolves TWO
// independent basis columns. Per-column data movement is bit-identical to the
// verified single-column path; loops are duplicated so col1's FMAs overlap
// col0's shuffle latency (ILP across independent dependency chains).
// amp index: bits 0..3 slot, 4..9 lane.
// ---------------------------------------------------------------------------
template <int Q>
__device__ __forceinline__ void rotT_gate2(
    float (&ar0)[16], float (&ai0)[16], float (&ar1)[16], float (&ai1)[16],
    int lane, const float* __restrict__ g) {
    float u00r = g[0], u00i = g[1];
    float u01r = g[4], u01i = g[5];   // transposed: u01 = orig u10
    float u10r = g[2], u10i = g[3];   // transposed: u10 = orig u01
    float u11r = g[6], u11i = g[7];
    if constexpr (Q < 4) {
#pragma unroll
        for (int j = 0; j < 16; ++j) {
            if ((j >> Q) & 1) continue;
            int j1 = j | (1 << Q);
            {
                float a0r = ar0[j],  a0i = ai0[j];
                float a1r = ar0[j1], a1i = ai0[j1];
                ar0[j]  = u00r*a0r - u00i*a0i + u01r*a1r - u01i*a1i;
                ai0[j]  = u00r*a0i + u00i*a0r + u01r*a1i + u01i*a1r;
                ar0[j1] = u10r*a0r - u10i*a0i + u11r*a1r - u11i*a1i;
                ai0[j1] = u10r*a0i + u10i*a0r + u11r*a1i + u11i*a1r;
            }
            {
                float a0r = ar1[j],  a0i = ai1[j];
                float a1r = ar1[j1], a1i = ai1[j1];
                ar1[j]  = u00r*a0r - u00i*a0i + u01r*a1r - u01i*a1i;
                ai1[j]  = u00r*a0i + u00i*a0r + u01r*a1i + u01i*a1r;
                ar1[j1] = u10r*a0r - u10i*a0i + u11r*a1r - u11i*a1i;
                ai1[j1] = u10r*a0i + u10i*a0r + u11r*a1i + u11i*a1r;
            }
        }
    } else {
        constexpr int M = 1 << (Q - 4);
        bool hi = (lane >> (Q - 4)) & 1;
        float car = hi ? u11r : u00r, cai = hi ? u11i : u00i;
        float cbr = hi ? u10r : u01r, cbi = hi ? u10i : u01i;
        float p0r[16], p0i[16], p1r[16], p1i[16];
#pragma unroll
        for (int j = 0; j < 16; ++j) p0r[j] = lane_xor<M>(ar0[j]);
#pragma unroll
        for (int j = 0; j < 16; ++j) p0i[j] = lane_xor<M>(ai0[j]);
#pragma unroll
        for (int j = 0; j < 16; ++j) p1r[j] = lane_xor<M>(ar1[j]);
#pragma unroll
        for (int j = 0; j < 16; ++j) p1i[j] = lane_xor<M>(ai1[j]);
#pragma unroll
        for (int j = 0; j < 16; ++j) {
            float mr = ar0[j], mi = ai0[j];
            ar0[j] = car*mr - cai*mi + cbr*p0r[j] - cbi*p0i[j];
            ai0[j] = car*mi + cai*mr + cbr*p0i[j] + cbi*p0r[j];
        }
#pragma unroll
        for (int j = 0; j < 16; ++j) {
            float mr = ar1[j], mi = ai1[j];
            ar1[j] = car*mr - cai*mi + cbr*p1r[j] - cbi*p1i[j];
            ai1[j] = car*mi + cai*mr + cbr*p1i[j] + cbi*p1r[j];
        }
    }
}

__device__ __forceinline__ void rotT_layer2(
    float (&ar0)[16], float (&ai0)[16], float (&ar1)[16], float (&ai1)[16],
    int lane, const float* __restrict__ gl) {
    rotT_gate2<0>(ar0, ai0, ar1, ai1, lane, gl + 0);
    rotT_gate2<1>(ar0, ai0, ar1, ai1, lane, gl + 8);
    rotT_gate2<2>(ar0, ai0, ar1, ai1, lane, gl + 16);
    rotT_gate2<3>(ar0, ai0, ar1, ai1, lane, gl + 24);
    rotT_gate2<4>(ar0, ai0, ar1, ai1, lane, gl + 32);
    rotT_gate2<5>(ar0, ai0, ar1, ai1, lane, gl + 40);
    rotT_gate2<6>(ar0, ai0, ar1, ai1, lane, gl + 48);
    rotT_gate2<7>(ar0, ai0, ar1, ai1, lane, gl + 56);
    rotT_gate2<8>(ar0, ai0, ar1, ai1, lane, gl + 64);
    rotT_gate2<9>(ar0, ai0, ar1, ai1, lane, gl + 72);
}

template <int C, int T>
__device__ __forceinline__ void cnot_t2(
    float (&ar0)[16], float (&ai0)[16], float (&ar1)[16], float (&ai1)[16],
    int lane) {
    if constexpr (C < 4 && T < 4) {
#pragma unroll
        for (int j = 0; j < 16; ++j) {
            if (((j >> C) & 1) && !((j >> T) & 1)) {
                int j1 = j | (1 << T);
                float t;
                t = ar0[j]; ar0[j] = ar0[j1]; ar0[j1] = t;
                t = ai0[j]; ai0[j] = ai0[j1]; ai0[j1] = t;
                t = ar1[j]; ar1[j] = ar1[j1]; ar1[j1] = t;
                t = ai1[j]; ai1[j] = ai1[j1]; ai1[j1] = t;
            }
        }
    } else if constexpr (C < 4) {
        constexpr int M = 1 << (T - 4);
        float p0r[16], p0i[16], p1r[16], p1i[16];
#pragma unroll
        for (int j = 0; j < 16; ++j)
            if ((j >> C) & 1) p0r[j] = lane_xor<M>(ar0[j]);
#pragma unroll
        for (int j = 0; j < 16; ++j)
            if ((j >> C) & 1) p0i[j] = lane_xor<M>(ai0[j]);
#pragma unroll
        for (int j = 0; j < 16; ++j)
            if ((j >> C) & 1) p1r[j] = lane_xor<M>(ar1[j]);
#pragma unroll
        for (int j = 0; j < 16; ++j)
            if ((j >> C) & 1) p1i[j] = lane_xor<M>(ai1[j]);
#pragma unroll
        for (int j = 0; j < 16; ++j)
            if ((j >> C) & 1) {
                ar0[j] = p0r[j]; ai0[j] = p0i[j];
                ar1[j] = p1r[j]; ai1[j] = p1i[j];
            }
    } else if constexpr (T < 4) {
        bool cb = (lane >> (C - 4)) & 1;
#pragma unroll
        for (int j = 0; j < 16; ++j) {
            if (!((j >> T) & 1)) {
                int j1 = j | (1 << T);
                {
                    float lr = ar0[j], li = ai0[j], hr = ar0[j1], hi2 = ai0[j1];
                    ar0[j]  = cb ? hr : lr;  ai0[j]  = cb ? hi2 : li;
                    ar0[j1] = cb ? lr : hr;  ai0[j1] = cb ? li : hi2;
                }
                {
                    float lr = ar1[j], li = ai1[j], hr = ar1[j1], hi2 = ai1[j1];
                    ar1[j]  = cb ? hr : lr;  ai1[j]  = cb ? hi2 : li;
                    ar1[j1] = cb ? lr : hr;  ai1[j1] = cb ? li : hi2;
                }
            }
        }
    } else {
        constexpr int M = 1 << (T - 4);
        bool cb = (lane >> (C - 4)) & 1;
        float p0r[16], p0i[16], p1r[16], p1i[16];
#pragma unroll
        for (int j = 0; j < 16; ++j) p0r[j] = lane_xor<M>(ar0[j]);
#pragma unroll
        for (int j = 0; j < 16; ++j) p0i[j] = lane_xor<M>(ai0[j]);
#pragma unroll
        for (int j = 0; j < 16; ++j) p1r[j] = lane_xor<M>(ar1[j]);
#pragma unroll
        for (int j = 0; j < 16; ++j) p1i[j] = lane_xor<M>(ai1[j]);
#pragma unroll
        for (int j = 0; j < 16; ++j) {
            ar0[j] = cb ? p0r[j] : ar0[j];
            ai0[j] = cb ? p0i[j] : ai0[j];
            ar1[j] = cb ? p1r[j] : ar1[j];
            ai1[j] = cb ? p1i[j] : ai1[j];
        }
    }
}

template <int R, int I>
__device__ __forceinline__ void cnot_ring_rev_t2(
    float (&ar0)[16], float (&ai0)[16], float (&ar1)[16], float (&ai1)[16],
    int lane) {
    cnot_t2<I, (I + R) % NQ>(ar0, ai0, ar1, ai1, lane);
    if constexpr (I > 0) cnot_ring_rev_t2<R, I - 1>(ar0, ai0, ar1, ai1, lane);
}

__device__ __forceinline__ void run_circuit_T2(
    float (&ar0)[16], float (&ai0)[16], float (&ar1)[16], float (&ai1)[16],
    const float* __restrict__ gmat, int lane) {
    for (int l = DEPTH - 1; l >= 0; --l) {
        switch (l) {
            case 0: cnot_ring_rev_t2<1, NQ - 1>(ar0, ai0, ar1, ai1, lane); break;
            case 1: cnot_ring_rev_t2<2, NQ - 1>(ar0, ai0, ar1, ai1, lane); break;
            case 2: cnot_ring_rev_t2<3, NQ - 1>(ar0, ai0, ar1, ai1, lane); break;
            case 3: cnot_ring_rev_t2<4, NQ - 1>(ar0, ai0, ar1, ai1, lane); break;
            case 4: cnot_ring_rev_t2<5, NQ - 1>(ar0, ai0, ar1, ai1, lane); break;
            default: cnot_ring_rev_t2<6, NQ - 1>(ar0, ai0, ar1, ai1, lane); break;
        }
        rotT_layer2(ar0, ai0, ar1, ai1, lane, gmat + l * (NQ * 8));
    }
}

__device__ __forceinline__ float wave_sum(float v) {
    v += lane_xor<1>(v);
    v += lane_xor<2>(v);
    v += lane_xor<4>(v);
    v += lane_xor<8>(v);
    v += lane_xor<16>(v);
    v += lane_xor<32>(v);
    return v;
}

// ---------------------------------------------------------------------------
// Generic (runtime-q) circuit helpers: used only by the vqc fallback.
// ---------------------------------------------------------------------------
__device__ __forceinline__ void apply_1q_local(
    float (&ar)[16], float (&ai)[16], int q,
    float u00r, float u00i, float u01r, float u01i,
    float u10r, float u10i, float u11r, float u11i) {
#pragma unroll
    for (int j = 0; j < 16; ++j) {
        if ((j >> q) & 1) continue;
        int j1 = j | (1 << q);
        float a0r = ar[j],  a0i = ai[j];
        float a1r = ar[j1], a1i = ai[j1];
        ar[j]  = u00r*a0r - u00i*a0i + u01r*a1r - u01i*a1i;
        ai[j]  = u00r*a0i + u00i*a0r + u01r*a1i + u01i*a1r;
        ar[j1] = u10r*a0r - u10i*a0i + u11r*a1r - u11i*a1i;
        ai[j1] = u10r*a0i + u10i*a0r + u11r*a1i + u11i*a1r;
    }
}

__device__ __forceinline__ void apply_1q_lane(
    float (&ar)[16], float (&ai)[16], int q, int lane,
    float u00r, float u00i, float u01r, float u01i,
    float u10r, float u10i, float u11r, float u11i) {
    int  m  = 1 << (q - 4);
    bool hi = (lane >> (q - 4)) & 1;
    float car = hi ? u11r : u00r, cai = hi ? u11i : u00i;
    float cbr = hi ? u10r : u01r, cbi = hi ? u10i : u01i;
    float pr[16], pi[16];
#pragma unroll
    for (int j = 0; j < 16; ++j) pr[j] = __shfl_xor(ar[j], m, 64);
#pragma unroll
    for (int j = 0; j < 16; ++j) pi[j] = __shfl_xor(ai[j], m, 64);
#pragma unroll
    for (int j = 0; j < 16; ++j) {
        float mr = ar[j], mi = ai[j];
        ar[j] = car*mr - cai*mi + cbr*pr[j] - cbi*pi[j];
        ai[j] = car*mi + cai*mr + cbr*pi[j] + cbi*pr[j];
    }
}

__device__ __forceinline__ void cnot_gate(
    float (&ar)[16], float (&ai)[16], int c, int t, int lane) {
    if (c < 4 && t < 4) {
#pragma unroll
        for (int j = 0; j < 16; ++j) {
            if (((j >> c) & 1) && !((j >> t) & 1)) {
                int j1 = j | (1 << t);
                float tr = ar[j]; ar[j] = ar[j1]; ar[j1] = tr;
                float ti = ai[j]; ai[j] = ai[j1]; ai[j1] = ti;
            }
        }
    } else if (c < 4) {
        int m = 1 << (t - 4);
        float pr[16], pi[16];
#pragma unroll
        for (int j = 0; j < 16; ++j)
            if ((j >> c) & 1) pr[j] = __shfl_xor(ar[j], m, 64);
#pragma unroll
        for (int j = 0; j < 16; ++j)
            if ((j >> c) & 1) pi[j] = __shfl_xor(ai[j], m, 64);
#pragma unroll
        for (int j = 0; j < 16; ++j)
            if ((j >> c) & 1) { ar[j] = pr[j]; ai[j] = pi[j]; }
    } else if (t < 4) {
        bool cb = (lane >> (c - 4)) & 1;
#pragma unroll
        for (int j = 0; j < 16; ++j) {
            if (!((j >> t) & 1)) {
                int j1 = j | (1 << t);
                float lr = ar[j], li = ai[j], hr = ar[j1], hi2 = ai[j1];
                ar[j]  = cb ? hr : lr;  ai[j]  = cb ? hi2 : li;
                ar[j1] = cb ? lr : hr;  ai[j1] = cb ? li : hi2;
            }
        }
    } else {
        int  m  = 1 << (t - 4);
        bool cb = (lane >> (c - 4)) & 1;
        float pr[16], pi[16];
#pragma unroll
        for (int j = 0; j < 16; ++j) pr[j] = __shfl_xor(ar[j], m, 64);
#pragma unroll
        for (int j = 0; j < 16; ++j) pi[j] = __shfl_xor(ai[j], m, 64);
#pragma unroll
        for (int j = 0; j < 16; ++j) {
            ar[j] = cb ? pr[j] : ar[j];
            ai[j] = cb ? pi[j] : ai[j];
        }
    }
}

template <int R>
__device__ __forceinline__ void cnot_ring(float (&ar)[16], float (&ai)[16], int lane) {
#pragma unroll
    for (int i = 0; i < NQ; ++i) cnot_gate(ar, ai, i, (i + R) % NQ, lane);
}

// forward circuit (fallback vqc_kernel)
__device__ __forceinline__ void run_circuit(float (&ar)[16], float (&ai)[16],
                                            const float* __restrict__ gmat, int lane) {
    for (int l = 0; l < DEPTH; ++l) {
        const float* gl = gmat + l * (NQ * 8);
#pragma unroll
        for (int i = 0; i < NQ; ++i) {
            const float* g = gl + i * 8;
            float u00r = g[0], u00i = g[1], u01r = g[2], u01i = g[3];
            float u10r = g[4], u10i = g[5], u11r = g[6], u11i = g[7];
            if (i < 4)
                apply_1q_local(ar, ai, i, u00r,u00i,u01r,u01i,u10r,u10i,u11r,u11i);
            else
                apply_1q_lane(ar, ai, i, lane, u00r,u00i,u01r,u01i,u10r,u10i,u11r,u11i);
        }
        switch (l) {
            case 0: cnot_ring<1>(ar, ai, lane); break;
            case 1: cnot_ring<2>(ar, ai, lane); break;
            case 2: cnot_ring<3>(ar, ai, lane); break;
            case 3: cnot_ring<4>(ar, ai, lane); break;
            case 4: cnot_ring<5>(ar, ai, lane); break;
            default: cnot_ring<6>(ar, ai, lane); break;
        }
    }
}

// ---------------------------------------------------------------------------
// proj body: float4 loads (verified round 10) + fast trig (verified r4).
// ---------------------------------------------------------------------------
__device__ __forceinline__ void proj_v_body(
    const float* __restrict__ x, const float* __restrict__ Wproj,
    _Float16* __restrict__ V, int b, int lane) {
    const float4* xb4 = (const float4*)(x + (size_t)b * 1024);
    const float4* W4  = (const float4*)Wproj;        // [q][256]
    float acc[NQ];
#pragma unroll
    for (int q = 0; q < NQ; ++q) acc[q] = 0.f;
#pragma unroll
    for (int k4 = 0; k4 < 4; ++k4) {
        float4 xv = xb4[k4 * 64 + lane];
#pragma unroll
        for (int q = 0; q < NQ; ++q) {
            float4 wv = W4[q * 256 + k4 * 64 + lane];
            acc[q] = fmaf(xv.x, wv.x, acc[q]);
            acc[q] = fmaf(xv.y, wv.y, acc[q]);
            acc[q] = fmaf(xv.z, wv.z, acc[q]);
            acc[q] = fmaf(xv.w, wv.w, acc[q]);
        }
    }
#pragma unroll
    for (int q = 0; q < NQ; ++q) acc[q] = wave_sum(acc[q]);

    float cq[NQ], sq[NQ];
#pragma unroll
    for (int q = 0; q < NQ; ++q) {
        float e  = __expf(2.f * acc[q]);
        float th = 1.f - __fdividef(2.f, e + 1.f);       // tanh(acc)
        float ha = th * 0.785398163397448310f;            // 0.5 * ang
        cq[q] = __cosf(ha);
        sq[q] = __sinf(ha);
    }
    float laneprod = 1.f;
#pragma unroll
    for (int q = 4; q < NQ; ++q)
        laneprod *= ((lane >> (q - 4)) & 1) ? sq[q] : cq[q];

    unsigned int buf[8];
#pragma unroll
    for (int jj = 0; jj < 8; ++jj) {
        unsigned short h2[2];
#pragma unroll
        for (int c = 0; c < 2; ++c) {
            int j = jj * 2 + c;
            float p = laneprod;
#pragma unroll
            for (int q = 0; q < 4; ++q) p *= ((j >> q) & 1) ? sq[q] : cq[q];
            h2[c] = __builtin_bit_cast(unsigned short, (_Float16)p);
        }
        buf[jj] = (unsigned int)h2[0] | ((unsigned int)h2[1] << 16);
    }
    uint4* dst = (uint4*)(V + (size_t)b * 1024 + 16 * lane);
    uint4 v0; v0.x = buf[0]; v0.y = buf[1]; v0.z = buf[2]; v0.w = buf[3];
    uint4 v1; v1.x = buf[4]; v1.y = buf[5]; v1.z = buf[6]; v1.w = buf[7];
    dst[0] = v0; dst[1] = v1;
}

// ---------------------------------------------------------------------------
// Kernel A: blocks [0,256): circuit — waves 0,1 each evolve TWO basis
//           columns (2-col ILP hides shuffle latency); waves 2,3 exit.
//           Per-CU circuit-wave count matches the verified r4 config.
//           blocks [256,...): projection -> V (4 rows/block, verified).
// ---------------------------------------------------------------------------
__global__ __launch_bounds__(256) void basis_proj_kernel(
    const float* __restrict__ weights, _Float16* __restrict__ Bt,
    const float* __restrict__ x, const float* __restrict__ Wproj,
    _Float16* __restrict__ V, int B) {
    __shared__ float gmat_s[DEPTH * NQ * 8];
    int tid  = threadIdx.x;
    int lane = tid & 63;
    int w    = tid >> 6;

    if (blockIdx.x < 256) {
        if (tid < DEPTH * NQ) compute_gate(weights, tid, gmat_s + tid * 8);
        __syncthreads();
        if (w >= 2) return;                  // 2 active waves per circuit block

        int g0 = blockIdx.x * 4 + w * 2;     // two columns per wave
        int g1 = g0 + 1;
        float ar0[16], ai0[16], ar1[16], ai1[16];
#pragma unroll
        for (int jj = 0; jj < 16; ++jj) {
            ar0[jj] = (lane == (g0 >> 4) && jj == (g0 & 15)) ? 1.f : 0.f;
            ai0[jj] = 0.f;
            ar1[jj] = (lane == (g1 >> 4) && jj == (g1 & 15)) ? 1.f : 0.f;
            ai1[jj] = 0.f;
        }
        run_circuit_T2(ar0, ai0, ar1, ai1, gmat_s, lane);

#pragma unroll
        for (int col = 0; col < 2; ++col) {
            const float* ar = col ? ar1 : ar0;
            const float* ai = col ? ai1 : ai0;
            int g = col ? g1 : g0;
            unsigned int bufr[8], bufi[8];
#pragma unroll
            for (int jj = 0; jj < 8; ++jj) {
                unsigned short r0 = __builtin_bit_cast(unsigned short, (_Float16)ar[2*jj]);
                unsigned short r1 = __builtin_bit_cast(unsigned short, (_Float16)ar[2*jj+1]);
                unsigned short i0 = __builtin_bit_cast(unsigned short, (_Float16)ai[2*jj]);
                unsigned short i1 = __builtin_bit_cast(unsigned short, (_Float16)ai[2*jj+1]);
                bufr[jj] = (unsigned int)r0 | ((unsigned int)r1 << 16);
                bufi[jj] = (unsigned int)i0 | ((unsigned int)i1 << 16);
            }
            uint4* dre = (uint4*)((unsigned short*)Bt + (size_t)(2*g)     * 1024 + 16 * lane);
            uint4* dim = (uint4*)((unsigned short*)Bt + (size_t)(2*g + 1) * 1024 + 16 * lane);
            uint4 v;
            v.x = bufr[0]; v.y = bufr[1]; v.z = bufr[2]; v.w = bufr[3]; dre[0] = v;
            v.x = bufr[4]; v.y = bufr[5]; v.z = bufr[6]; v.w = bufr[7]; dre[1] = v;
            v.x = bufi[0]; v.y = bufi[1]; v.z = bufi[2]; v.w = bufi[3]; dim[0] = v;
            v.x = bufi[4]; v.y = bufi[5]; v.z = bufi[6]; v.w = bufi[7]; dim[1] = v;
        }
    } else {
        int b = (blockIdx.x - 256) * 4 + w;
        if (b < B) proj_v_body(x, Wproj, V, b, lane);
    }
}

// ---------------------------------------------------------------------------
// Kernel B: fused GEMM + |psi|^2 + partial-Z reduction (round-4 verified:
// BK=32 phase pipeline, quad-buffered LDS, counted vmcnt(8); Zpart output).
// ---------------------------------------------------------------------------
#define STG(dst_, src_, kt_) do {                                                   \
    _Pragma("unroll")                                                               \
    for (int s_ = 0; s_ < 2; ++s_) {                                                \
        async_load16(src_ + (size_t)(s_ * 128 + srow) * 1024 + (kt_) * 32 + scg * 8,\
                     dst_ + s_ * 4096 + w * 512);                                   \
    }                                                                               \
} while (0)

__global__ __launch_bounds__(512, 2) void gemm_fused_kernel(
    const unsigned short* __restrict__ A,    // V (B,1024)
    const unsigned short* __restrict__ Bt,   // (2048,1024)
    float* __restrict__ Zpart) {             // (B,16,8)
    __shared__ __align__(16) unsigned short lds_s[4 * 16384];  // 128 KiB
    int tid  = threadIdx.x;
    int lane = tid & 63;
    int w    = tid >> 6;                 // 0..7
    int wm   = w >> 2;                   // 0..1 : 128-row half
    int wn   = w & 3;                    // 0..3 : 64-col quarter
    int by   = blockIdx.x & 7;           // XCD id -> Bt panel (L2 locality)
    int bx   = blockIdx.x >> 3;
    int m0   = bx * 256;
    int n0   = by * 256;
    int quad = lane >> 4;
    int lrow = lane & 15;
    int csw  = (quad ^ ((lrow >> 1) & 3)) * 8;   // swizzled read-chunk offset (shorts)
    int srow = tid >> 2;                          // staging row within 128-row sweep
    int scg  = (tid & 3) ^ ((srow >> 1) & 3);     // swizzled source chunk
    const unsigned short* Abase = A  + (size_t)m0 * 1024;
    const unsigned short* Bbase = Bt + (size_t)n0 * 1024;

    f32x4 acc[8][4];
#pragma unroll
    for (int mi = 0; mi < 8; ++mi)
#pragma unroll
        for (int ni = 0; ni < 4; ++ni)
            acc[mi][ni] = (f32x4){0.f, 0.f, 0.f, 0.f};

    // prologue: stage tiles 0,1,2 (12 loads); validate tile 0
    STG(lds_s + 0 * 16384,        Abase, 0);
    STG(lds_s + 0 * 16384 + 8192, Bbase, 0);
    STG(lds_s + 1 * 16384,        Abase, 1);
    STG(lds_s + 1 * 16384 + 8192, Bbase, 1);
    STG(lds_s + 2 * 16384,        Abase, 2);
    STG(lds_s + 2 * 16384 + 8192, Bbase, 2);
    asm volatile("s_waitcnt vmcnt(8)" ::: "memory");
    __builtin_amdgcn_s_barrier();

    int rowA = wm * 128 + lrow;          // + mi*16
    int rowB = wn * 64  + lrow;          // + ni*16

    for (int t = 0; t < 32; ++t) {
        const unsigned short* bufA = lds_s + (t & 3) * 16384;
        const unsigned short* bufB = bufA + 8192;
        unsigned short* nbuf = lds_s + ((t + 3) & 3) * 16384;
        f16x8 af[4], bf[4];
        // ---------------- phase 0: mi 0..3 ----------------
#pragma unroll
        for (int i = 0; i < 4; ++i)
            af[i] = *(const f16x8*)(bufA + (rowA + i * 16) * 32 + csw);
#pragma unroll
        for (int i = 0; i < 4; ++i)
            bf[i] = *(const f16x8*)(bufB + (rowB + i * 16) * 32 + csw);
        if (t < 29) STG(nbuf, Abase, t + 3);
        __builtin_amdgcn_s_barrier();
        asm volatile("s_waitcnt lgkmcnt(0)" ::: "memory");
        __builtin_amdgcn_sched_barrier(0);
        __builtin_amdgcn_s_setprio(1);
#pragma unroll
        for (int mi = 0; mi < 4; ++mi)
#pragma unroll
            for (int ni = 0; ni < 4; ++ni)
                acc[mi][ni] = __builtin_amdgcn_mfma_f32_16x16x32_f16(
                    af[mi], bf[ni], acc[mi][ni], 0, 0, 0);
        __builtin_amdgcn_s_setprio(0);
        __builtin_amdgcn_s_barrier();
        // ---------------- phase 1: mi 4..7 ----------------
#pragma unroll
        for (int i = 0; i < 4; ++i)
            af[i] = *(const f16x8*)(bufA + (rowA + 64 + i * 16) * 32 + csw);
        if (t < 29) {
            STG(nbuf + 8192, Bbase, t + 3);
            asm volatile("s_waitcnt vmcnt(8)" ::: "memory");   // validate t+1
        } else {
            asm volatile("s_waitcnt vmcnt(0)" ::: "memory");   // 3-tile tail drain
        }
        __builtin_amdgcn_s_barrier();
        asm volatile("s_waitcnt lgkmcnt(0)" ::: "memory");
        __builtin_amdgcn_sched_barrier(0);
        __builtin_amdgcn_s_setprio(1);
#pragma unroll
        for (int mi = 0; mi < 4; ++mi)
#pragma unroll
            for (int ni = 0; ni < 4; ++ni)
                acc[mi + 4][ni] = __builtin_amdgcn_mfma_f32_16x16x32_f16(
                    af[mi], bf[ni], acc[mi + 4][ni], 0, 0, 0);
        __builtin_amdgcn_s_setprio(0);
        __builtin_amdgcn_s_barrier();
    }

    // ---- epilogue: square + signed reduce (stride-9 LDS, conflict-free) ----
    float* Zs = (float*)lds_s;                 // [2 nb][2 half][256 rows][9]
    int nbl  = wn >> 1;
    int half = wn & 1;
#pragma unroll
    for (int mi = 0; mi < 8; ++mi) {
#pragma unroll
        for (int r = 0; r < 4; ++r) {
            float p0 = acc[mi][0][r] * acc[mi][0][r];
            float p1 = acc[mi][1][r] * acc[mi][1][r];
            float p2 = acc[mi][2][r] * acc[mi][2][r];
            float p3 = acc[mi][3][r] * acc[mi][3][r];
            float t0 = (p0 + p1) + (p2 + p3);
            float t3 = (p0 - p1) + (p2 - p3);
            float t4 = (p0 + p1) - (p2 + p3);
            t0 += lane_xor<1>(t0);
            t3 += lane_xor<1>(t3);
            t4 += lane_xor<1>(t4);
            float u2 = lane_xor<2>(t0);
            float ap = t0 + u2;
            float am = (lane & 2) ? u2 - t0 : t0 - u2;
            t3 += lane_xor<2>(t3);
            t4 += lane_xor<2>(t4);
            float u4  = lane_xor<4>(ap);
            float bpp = ap + u4;
            float bpm = (lane & 4) ? u4 - ap : ap - u4;
            float bmp = am + lane_xor<4>(am);
            t3 += lane_xor<4>(t3);
            t4 += lane_xor<4>(t4);
            float u8 = lane_xor<8>(bpp);
            float T  = bpp + u8;
            float Z2 = (lane & 8) ? u8 - bpp : bpp - u8;
            float Z1 = bpm + lane_xor<8>(bpm);
            float Z0 = bmp + lane_xor<8>(bmp);
            t3 += lane_xor<8>(t3);
            t4 += lane_xor<8>(t4);
            if (lrow == 0) {
                int row = wm * 128 + mi * 16 + quad * 4 + r;
                float* z = Zs + ((size_t)(nbl * 2 + half) * 256 + row) * 9;
                z[0] = T;  z[1] = Z0; z[2] = Z1; z[3] = Z2;
                z[4] = t3; z[5] = t4;
            }
        }
    }
    __syncthreads();
    {
        int row  = tid >> 1, part = tid & 1;   // 256 rows x 2 parts = 512 threads
#pragma unroll
        for (int nb = 0; nb < 2; ++nb) {
            const float* za = Zs + ((size_t)(nb * 2 + 0) * 256 + row) * 9;
            const float* zb = Zs + ((size_t)(nb * 2 + 1) * 256 + row) * 9;
            float o[4];
            if (part == 0) {
                o[0] = za[0] + zb[0];            // T
                o[1] = za[1] + zb[1];            // Z0
                o[2] = za[2] + zb[2];            // Z1
                o[3] = za[3] + zb[3];            // Z2
            } else {
                o[0] = za[4] + zb[4];            // Z3
                o[1] = za[5] + zb[5];            // Z4
                o[2] = za[0] - zb[0];            // Z5
                o[3] = 0.f;
            }
            float4 v = {o[0], o[1], o[2], o[3]};
            *(float4*)(Zpart + ((size_t)(m0 + row) * 16 + (by * 2 + nb)) * 8 + part * 4) = v;
        }
    }
}

// ---------------------------------------------------------------------------
// Kernel C: combine 16 n-tile partials -> Z_q -> output head (verified r8).
// ---------------------------------------------------------------------------
__global__ __launch_bounds__(256) void combine_head_kernel(
    const float* __restrict__ Zpart, const float* __restrict__ Wout,
    const float* __restrict__ bout, float* __restrict__ out, int B) {
    int lane = threadIdx.x & 63;
    int wid  = threadIdx.x >> 6;
    int b    = blockIdx.x * 4 + wid;
    if (b >= B) return;

    float z[8];
    if (lane < 16) {
        const float4* p = (const float4*)(Zpart + ((size_t)b * 16 + lane) * 8);
        float4 a = p[0], c = p[1];
        z[0]=a.x; z[1]=a.y; z[2]=a.z; z[3]=a.w; z[4]=c.x; z[5]=c.y; z[6]=c.z; z[7]=c.w;
    } else {
#pragma unroll
        for (int i = 0; i < 8; ++i) z[i] = 0.f;
    }
    float Zq[NQ];
#pragma unroll
    for (int q = 0; q < 6; ++q) {
        float v = z[q + 1];
        v += lane_xor<1>(v);
        v += lane_xor<2>(v);
        v += lane_xor<4>(v);
        v += lane_xor<8>(v);
        Zq[q] = v;
    }
    {
        float T = z[0];
        float u1 = lane_xor<1>(T);
        float P  = T + u1;
        float M  = (lane & 1) ? u1 - T : T - u1;
        float u2 = lane_xor<2>(P);
        float PP = P + u2;
        float PM = (lane & 2) ? u2 - P : P - u2;
        float MP = M + lane_xor<2>(M);
        float u4  = lane_xor<4>(PP);
        float PPP = PP + u4;
        float PPM = (lane & 4) ? u4 - PP : PP - u4;
        float PMP = PM + lane_xor<4>(PM);
        float MPP = MP + lane_xor<4>(MP);
        float u8 = lane_xor<8>(PPP);
        Zq[9] = (lane & 8) ? u8 - PPP : PPP - u8;
        Zq[8] = PPM + lane_xor<8>(PPM);
        Zq[7] = PMP + lane_xor<8>(PMP);
        Zq[6] = MPP + lane_xor<8>(MPP);
    }
    if (lane < NQ) {
        float o = bout[lane];
#pragma unroll
        for (int q = 0; q < NQ; ++q) o = fmaf(Zq[q], Wout[lane * NQ + q], o);
        out[(size_t)b * NQ + lane] = o;
    }
}

// ---------------------------------------------------------------------------
// Fallback: round-1 monolithic kernel (verified).
// ---------------------------------------------------------------------------
__global__ __launch_bounds__(256) void vqc_kernel(
    const float* __restrict__ x, const float* __restrict__ Wproj,
    const float* __restrict__ gmat, const float* __restrict__ Wout,
    const float* __restrict__ bout, float* __restrict__ out, int B) {
    int lane = threadIdx.x & 63;
    int wid  = threadIdx.x >> 6;
    int b    = blockIdx.x * 4 + wid;
    if (b >= B) return;

    const float* xb = x + (size_t)b * 1024;
    float acc[NQ];
#pragma unroll
    for (int q = 0; q < NQ; ++q) acc[q] = 0.f;
#pragma unroll
    for (int k = 0; k < 16; ++k) {
        float xv = xb[k * 64 + lane];
#pragma unroll
        for (int q = 0; q < NQ; ++q)
            acc[q] = fmaf(xv, Wproj[q * 1024 + k * 64 + lane], acc[q]);
    }
#pragma unroll
    for (int q = 0; q < NQ; ++q) acc[q] = wave_sum(acc[q]);

    float cq[NQ], sq[NQ];
#pragma unroll
    for (int q = 0; q < NQ; ++q) {
        float ang = tanhf(acc[q]) * 1.57079632679489662f;
        cq[q] = cosf(0.5f * ang);
        sq[q] = sinf(0.5f * ang);
    }
    float laneprod = 1.f;
#pragma unroll
    for (int q = 4; q < NQ; ++q)
        laneprod *= ((lane >> (q - 4)) & 1) ? sq[q] : cq[q];
    float ar[16], ai[16];
#pragma unroll
    for (int j = 0; j < 16; ++j) {
        float p = laneprod;
#pragma unroll
        for (int q = 0; q < 4; ++q) p *= ((j >> q) & 1) ? sq[q] : cq[q];
        ar[j] = p; ai[j] = 0.f;
    }
    run_circuit(ar, ai, gmat, lane);

    float T = 0.f, S[4] = {0.f, 0.f, 0.f, 0.f};
#pragma unroll
    for (int j = 0; j < 16; ++j) {
        float p = ar[j] * ar[j] + ai[j] * ai[j];
        T += p;
#pragma unroll
        for (int q = 0; q < 4; ++q) S[q] += ((j >> q) & 1) ? -p : p;
    }
    float Zq[NQ];
#pragma unroll
    for (int q = 0; q < 4; ++q) Zq[q] = S[q];
#pragma unroll
    for (int q = 4; q < NQ; ++q) Zq[q] = ((lane >> (q - 4)) & 1) ? -T : T;
#pragma unroll
    for (int q = 0; q < NQ; ++q) Zq[q] = wave_sum(Zq[q]);
    if (lane < NQ) {
        float o = bout[lane];
#pragma unroll
        for (int q = 0; q < NQ; ++q) o = fmaf(Zq[q], Wout[lane * NQ + q], o);
        out[(size_t)b * NQ + lane] = o;
    }
}

extern "C" void kernel_launch(void* const* d_in, const int* in_sizes, int n_in,
                              void* d_out, int out_size, void* d_ws, size_t ws_size,
                              hipStream_t stream) {
    const float* x       = (const float*)d_in[0];
    const float* Wproj   = (const float*)d_in[1];
    const float* weights = (const float*)d_in[2];
    const float* Wout    = (const float*)d_in[3];
    const float* bout    = (const float*)d_in[4];
    float* out = (float*)d_out;
    int B = in_sizes[0] / 1024;

    char* ws = (char*)d_ws;
    size_t off_Bt = 4096;
    size_t off_V  = off_Bt + (size_t)2048 * 1024 * 2;
    size_t off_Z  = off_V  + (size_t)B * 1024 * 2;
    size_t need   = off_Z  + (size_t)B * 16 * 8 * 4;

    if (ws_size >= need && (B % 256) == 0) {
        _Float16* Bt = (_Float16*)(ws + off_Bt);
        _Float16* V  = (_Float16*)(ws + off_V);
        float*  Zprt = (float*)(ws + off_Z);

        basis_proj_kernel<<<256 + B / 4, 256, 0, stream>>>(weights, Bt, x, Wproj, V, B);
        gemm_fused_kernel<<<(B / 256) * 8, 512, 0, stream>>>(
            (const unsigned short*)V, (const unsigned short*)Bt, Zprt);
        combine_head_kernel<<<B / 4, 256, 0, stream>>>(Zprt, Wout, bout, out, B);
    } else {
        float* gmat = (float*)ws;
        prep_gates_kernel<<<1, 64, 0, stream>>>(weights, gmat);
        vqc_kernel<<<(B + 3) / 4, 256, 0, stream>>>(x, Wproj, gmat, Wout, bout, out, B);
    }
}

// Round 8
// 141.696 us; speedup vs baseline: 1.1904x; 1.1446x over previous
//
#include <hip/hip_runtime.h>
#include <math.h>
#include <stdint.h>

#define NQ 10
#define DEPTH 6

typedef _Float16 f16x8 __attribute__((ext_vector_type(8)));
typedef float f32x4 __attribute__((ext_vector_type(4)));

typedef __attribute__((address_space(3))) unsigned int lds_u32;
typedef const __attribute__((address_space(1))) unsigned int glb_u32;

__device__ __forceinline__ void async_load16(const unsigned short* g, unsigned short* l) {
    __builtin_amdgcn_global_load_lds((glb_u32*)g, (lds_u32*)l, 16, 0, 0);
}

// ---------------------------------------------------------------------------
// lane_xor<M>: bitwise-identical replacement for __shfl_xor(v, M, 64).
// ---------------------------------------------------------------------------
template <int M>
__device__ __forceinline__ float lane_xor(float v) {
    if constexpr (M == 1) {
        int r = __builtin_amdgcn_update_dpp(
            __builtin_bit_cast(int, v), __builtin_bit_cast(int, v),
            0xB1, 0xF, 0xF, false);                       // quad_perm [1,0,3,2]
        return __builtin_bit_cast(float, r);
    } else if constexpr (M == 2) {
        int r = __builtin_amdgcn_update_dpp(
            __builtin_bit_cast(int, v), __builtin_bit_cast(int, v),
            0x4E, 0xF, 0xF, false);                       // quad_perm [2,3,0,1]
        return __builtin_bit_cast(float, r);
    } else if constexpr (M == 4) {
        return __builtin_bit_cast(float,
            __builtin_amdgcn_ds_swizzle(__builtin_bit_cast(int, v), 0x101F));
    } else if constexpr (M == 8) {
        return __builtin_bit_cast(float,
            __builtin_amdgcn_ds_swizzle(__builtin_bit_cast(int, v), 0x201F));
    } else if constexpr (M == 16) {
        return __builtin_bit_cast(float,
            __builtin_amdgcn_ds_swizzle(__builtin_bit_cast(int, v), 0x401F));
    } else {
        return __shfl_xor(v, 32, 64);
    }
}

// ---------------------------------------------------------------------------
// Gate precompute: Rot = RZ(omega) RY(theta) RZ(phi)
// ---------------------------------------------------------------------------
__device__ __forceinline__ void compute_gate(const float* __restrict__ weights,
                                             int idx, float* __restrict__ g) {
    float phi   = weights[idx * 3 + 0];
    float theta = weights[idx * 3 + 1];
    float omega = weights[idx * 3 + 2];
    float c = cosf(0.5f * theta), s = sinf(0.5f * theta);
    float ap = -0.5f * (phi + omega);
    float am = -0.5f * (phi - omega);
    float epr = cosf(ap), epi = sinf(ap);
    float emr = cosf(am), emi = sinf(am);
    g[0] =  epr * c;  g[1] =  epi * c;
    g[2] = -emr * s;  g[3] =  emi * s;
    g[4] =  emr * s;  g[5] =  emi * s;
    g[6] =  epr * c;  g[7] = -epi * c;
}

__global__ void prep_gates_kernel(const float* __restrict__ weights,
                                  float* __restrict__ gmat) {
    int idx = blockIdx.x * blockDim.x + threadIdx.x;
    if (idx >= DEPTH * NQ) return;
    compute_gate(weights, idx, gmat + idx * 8);
}

// ---------------------------------------------------------------------------
// Templated single-column transposed circuit (bench4-verified fastest).
// amp index: bits 0..3 slot, 4..9 lane.
// ---------------------------------------------------------------------------
template <int Q>
__device__ __forceinline__ void rotT_gate(float (&ar)[16], float (&ai)[16], int lane,
                                          const float* __restrict__ g) {
    float u00r = g[0], u00i = g[1];
    float u01r = g[4], u01i = g[5];   // transposed: u01 = orig u10
    float u10r = g[2], u10i = g[3];   // transposed: u10 = orig u01
    float u11r = g[6], u11i = g[7];
    if constexpr (Q < 4) {
#pragma unroll
        for (int j = 0; j < 16; ++j) {
            if ((j >> Q) & 1) continue;
            int j1 = j | (1 << Q);
            float a0r = ar[j],  a0i = ai[j];
            float a1r = ar[j1], a1i = ai[j1];
            ar[j]  = u00r*a0r - u00i*a0i + u01r*a1r - u01i*a1i;
            ai[j]  = u00r*a0i + u00i*a0r + u01r*a1i + u01i*a1r;
            ar[j1] = u10r*a0r - u10i*a0i + u11r*a1r - u11i*a1i;
            ai[j1] = u10r*a0i + u10i*a0r + u11r*a1i + u11i*a1r;
        }
    } else {
        constexpr int M = 1 << (Q - 4);
        bool hi = (lane >> (Q - 4)) & 1;
        float car = hi ? u11r : u00r, cai = hi ? u11i : u00i;
        float cbr = hi ? u10r : u01r, cbi = hi ? u10i : u01i;
        float pr[16], pi[16];
#pragma unroll
        for (int j = 0; j < 16; ++j) pr[j] = lane_xor<M>(ar[j]);
#pragma unroll
        for (int j = 0; j < 16; ++j) pi[j] = lane_xor<M>(ai[j]);
#pragma unroll
        for (int j = 0; j < 16; ++j) {
            float mr = ar[j], mi = ai[j];
            ar[j] = car*mr - cai*mi + cbr*pr[j] - cbi*pi[j];
            ai[j] = car*mi + cai*mr + cbr*pi[j] + cbi*pr[j];
        }
    }
}

__device__ __forceinline__ void rotT_layer(float (&ar)[16], float (&ai)[16], int lane,
                                           const float* __restrict__ gl) {
    rotT_gate<0>(ar, ai, lane, gl + 0);
    rotT_gate<1>(ar, ai, lane, gl + 8);
    rotT_gate<2>(ar, ai, lane, gl + 16);
    rotT_gate<3>(ar, ai, lane, gl + 24);
    rotT_gate<4>(ar, ai, lane, gl + 32);
    rotT_gate<5>(ar, ai, lane, gl + 40);
    rotT_gate<6>(ar, ai, lane, gl + 48);
    rotT_gate<7>(ar, ai, lane, gl + 56);
    rotT_gate<8>(ar, ai, lane, gl + 64);
    rotT_gate<9>(ar, ai, lane, gl + 72);
}

template <int C, int T>
__device__ __forceinline__ void cnot_t(float (&ar)[16], float (&ai)[16], int lane) {
    if constexpr (C < 4 && T < 4) {
#pragma unroll
        for (int j = 0; j < 16; ++j) {
            if (((j >> C) & 1) && !((j >> T) & 1)) {
                int j1 = j | (1 << T);
                float tr = ar[j]; ar[j] = ar[j1]; ar[j1] = tr;
                float ti = ai[j]; ai[j] = ai[j1]; ai[j1] = ti;
            }
        }
    } else if constexpr (C < 4) {
        constexpr int M = 1 << (T - 4);
        float pr[16], pi[16];
#pragma unroll
        for (int j = 0; j < 16; ++j)
            if ((j >> C) & 1) pr[j] = lane_xor<M>(ar[j]);
#pragma unroll
        for (int j = 0; j < 16; ++j)
            if ((j >> C) & 1) pi[j] = lane_xor<M>(ai[j]);
#pragma unroll
        for (int j = 0; j < 16; ++j)
            if ((j >> C) & 1) { ar[j] = pr[j]; ai[j] = pi[j]; }
    } else if constexpr (T < 4) {
        bool cb = (lane >> (C - 4)) & 1;
#pragma unroll
        for (int j = 0; j < 16; ++j) {
            if (!((j >> T) & 1)) {
                int j1 = j | (1 << T);
                float lr = ar[j], li = ai[j], hr = ar[j1], hi2 = ai[j1];
                ar[j]  = cb ? hr : lr;  ai[j]  = cb ? hi2 : li;
                ar[j1] = cb ? lr : hr;  ai[j1] = cb ? li : hi2;
            }
        }
    } else {
        constexpr int M = 1 << (T - 4);
        bool cb = (lane >> (C - 4)) & 1;
        float pr[16], pi[16];
#pragma unroll
        for (int j = 0; j < 16; ++j) pr[j] = lane_xor<M>(ar[j]);
#pragma unroll
        for (int j = 0; j < 16; ++j) pi[j] = lane_xor<M>(ai[j]);
#pragma unroll
        for (int j = 0; j < 16; ++j) {
            ar[j] = cb ? pr[j] : ar[j];
            ai[j] = cb ? pi[j] : ai[j];
        }
    }
}

template <int R, int I>
__device__ __forceinline__ void cnot_ring_rev_t(float (&ar)[16], float (&ai)[16], int lane) {
    cnot_t<I, (I + R) % NQ>(ar, ai, lane);
    if constexpr (I > 0) cnot_ring_rev_t<R, I - 1>(ar, ai, lane);
}

__device__ __forceinline__ void run_circuit_T(float (&ar)[16], float (&ai)[16],
                                              const float* __restrict__ gmat, int lane) {
    for (int l = DEPTH - 1; l >= 0; --l) {
        switch (l) {
            case 0: cnot_ring_rev_t<1, NQ - 1>(ar, ai, lane); break;
            case 1: cnot_ring_rev_t<2, NQ - 1>(ar, ai, lane); break;
            case 2: cnot_ring_rev_t<3, NQ - 1>(ar, ai, lane); break;
            case 3: cnot_ring_rev_t<4, NQ - 1>(ar, ai, lane); break;
            case 4: cnot_ring_rev_t<5, NQ - 1>(ar, ai, lane); break;
            default: cnot_ring_rev_t<6, NQ - 1>(ar, ai, lane); break;
        }
        rotT_layer(ar, ai, lane, gmat + l * (NQ * 8));
    }
}

__device__ __forceinline__ float wave_sum(float v) {
    v += lane_xor<1>(v);
    v += lane_xor<2>(v);
    v += lane_xor<4>(v);
    v += lane_xor<8>(v);
    v += lane_xor<16>(v);
    v += lane_xor<32>(v);
    return v;
}

// ---------------------------------------------------------------------------
// Generic (runtime-q) circuit helpers: used only by the vqc fallback.
// ---------------------------------------------------------------------------
__device__ __forceinline__ void apply_1q_local(
    float (&ar)[16], float (&ai)[16], int q,
    float u00r, float u00i, float u01r, float u01i,
    float u10r, float u10i, float u11r, float u11i) {
#pragma unroll
    for (int j = 0; j < 16; ++j) {
        if ((j >> q) & 1) continue;
        int j1 = j | (1 << q);
        float a0r = ar[j],  a0i = ai[j];
        float a1r = ar[j1], a1i = ai[j1];
        ar[j]  = u00r*a0r - u00i*a0i + u01r*a1r - u01i*a1i;
        ai[j]  = u00r*a0i + u00i*a0r + u01r*a1i + u01i*a1r;
        ar[j1] = u10r*a0r - u10i*a0i + u11r*a1r - u11i*a1i;
        ai[j1] = u10r*a0i + u10i*a0r + u11r*a1i + u11i*a1r;
    }
}

__device__ __forceinline__ void apply_1q_lane(
    float (&ar)[16], float (&ai)[16], int q, int lane,
    float u00r, float u00i, float u01r, float u01i,
    float u10r, float u10i, float u11r, float u11i) {
    int  m  = 1 << (q - 4);
    bool hi = (lane >> (q - 4)) & 1;
    float car = hi ? u11r : u00r, cai = hi ? u11i : u00i;
    float cbr = hi ? u10r : u01r, cbi = hi ? u10i : u01i;
    float pr[16], pi[16];
#pragma unroll
    for (int j = 0; j < 16; ++j) pr[j] = __shfl_xor(ar[j], m, 64);
#pragma unroll
    for (int j = 0; j < 16; ++j) pi[j] = __shfl_xor(ai[j], m, 64);
#pragma unroll
    for (int j = 0; j < 16; ++j) {
        float mr = ar[j], mi = ai[j];
        ar[j] = car*mr - cai*mi + cbr*pr[j] - cbi*pi[j];
        ai[j] = car*mi + cai*mr + cbr*pi[j] + cbi*pr[j];
    }
}

__device__ __forceinline__ void cnot_gate(
    float (&ar)[16], float (&ai)[16], int c, int t, int lane) {
    if (c < 4 && t < 4) {
#pragma unroll
        for (int j = 0; j < 16; ++j) {
            if (((j >> c) & 1) && !((j >> t) & 1)) {
                int j1 = j | (1 << t);
                float tr = ar[j]; ar[j] = ar[j1]; ar[j1] = tr;
                float ti = ai[j]; ai[j] = ai[j1]; ai[j1] = ti;
            }
        }
    } else if (c < 4) {
        int m = 1 << (t - 4);
        float pr[16], pi[16];
#pragma unroll
        for (int j = 0; j < 16; ++j)
            if ((j >> c) & 1) pr[j] = __shfl_xor(ar[j], m, 64);
#pragma unroll
        for (int j = 0; j < 16; ++j)
            if ((j >> c) & 1) pi[j] = __shfl_xor(ai[j], m, 64);
#pragma unroll
        for (int j = 0; j < 16; ++j)
            if ((j >> c) & 1) { ar[j] = pr[j]; ai[j] = pi[j]; }
    } else if (t < 4) {
        bool cb = (lane >> (c - 4)) & 1;
#pragma unroll
        for (int j = 0; j < 16; ++j) {
            if (!((j >> t) & 1)) {
                int j1 = j | (1 << t);
                float lr = ar[j], li = ai[j], hr = ar[j1], hi2 = ai[j1];
                ar[j]  = cb ? hr : lr;  ai[j]  = cb ? hi2 : li;
                ar[j1] = cb ? lr : hr;  ai[j1] = cb ? li : hi2;
            }
        }
    } else {
        int  m  = 1 << (t - 4);
        bool cb = (lane >> (c - 4)) & 1;
        float pr[16], pi[16];
#pragma unroll
        for (int j = 0; j < 16; ++j) pr[j] = __shfl_xor(ar[j], m, 64);
#pragma unroll
        for (int j = 0; j < 16; ++j) pi[j] = __shfl_xor(ai[j], m, 64);
#pragma unroll
        for (int j = 0; j < 16; ++j) {
            ar[j] = cb ? pr[j] : ar[j];
            ai[j] = cb ? pi[j] : ai[j];
        }
    }
}

template <int R>
__device__ __forceinline__ void cnot_ring(float (&ar)[16], float (&ai)[16], int lane) {
#pragma unroll
    for (int i = 0; i < NQ; ++i) cnot_gate(ar, ai, i, (i + R) % NQ, lane);
}

// forward circuit (fallback vqc_kernel)
__device__ __forceinline__ void run_circuit(float (&ar)[16], float (&ai)[16],
                                            const float* __restrict__ gmat, int lane) {
    for (int l = 0; l < DEPTH; ++l) {
        const float* gl = gmat + l * (NQ * 8);
#pragma unroll
        for (int i = 0; i < NQ; ++i) {
            const float* g = gl + i * 8;
            float u00r = g[0], u00i = g[1], u01r = g[2], u01i = g[3];
            float u10r = g[4], u10i = g[5], u11r = g[6], u11i = g[7];
            if (i < 4)
                apply_1q_local(ar, ai, i, u00r,u00i,u01r,u01i,u10r,u10i,u11r,u11i);
            else
                apply_1q_lane(ar, ai, i, lane, u00r,u00i,u01r,u01i,u10r,u10i,u11r,u11i);
        }
        switch (l) {
            case 0: cnot_ring<1>(ar, ai, lane); break;
            case 1: cnot_ring<2>(ar, ai, lane); break;
            case 2: cnot_ring<3>(ar, ai, lane); break;
            case 3: cnot_ring<4>(ar, ai, lane); break;
            case 4: cnot_ring<5>(ar, ai, lane); break;
            default: cnot_ring<6>(ar, ai, lane); break;
        }
    }
}

// ---------------------------------------------------------------------------
// proj body: float4 loads + fast trig (bench4-verified).
// ---------------------------------------------------------------------------
__device__ __forceinline__ void proj_v_body(
    const float* __restrict__ x, const float* __restrict__ Wproj,
    _Float16* __restrict__ V, int b, int lane) {
    const float4* xb4 = (const float4*)(x + (size_t)b * 1024);
    const float4* W4  = (const float4*)Wproj;        // [q][256]
    float acc[NQ];
#pragma unroll
    for (int q = 0; q < NQ; ++q) acc[q] = 0.f;
#pragma unroll
    for (int k4 = 0; k4 < 4; ++k4) {
        float4 xv = xb4[k4 * 64 + lane];
#pragma unroll
        for (int q = 0; q < NQ; ++q) {
            float4 wv = W4[q * 256 + k4 * 64 + lane];
            acc[q] = fmaf(xv.x, wv.x, acc[q]);
            acc[q] = fmaf(xv.y, wv.y, acc[q]);
            acc[q] = fmaf(xv.z, wv.z, acc[q]);
            acc[q] = fmaf(xv.w, wv.w, acc[q]);
        }
    }
#pragma unroll
    for (int q = 0; q < NQ; ++q) acc[q] = wave_sum(acc[q]);

    float cq[NQ], sq[NQ];
#pragma unroll
    for (int q = 0; q < NQ; ++q) {
        float e  = __expf(2.f * acc[q]);
        float th = 1.f - __fdividef(2.f, e + 1.f);       // tanh(acc)
        float ha = th * 0.785398163397448310f;            // 0.5 * ang
        cq[q] = __cosf(ha);
        sq[q] = __sinf(ha);
    }
    float laneprod = 1.f;
#pragma unroll
    for (int q = 4; q < NQ; ++q)
        laneprod *= ((lane >> (q - 4)) & 1) ? sq[q] : cq[q];

    unsigned int buf[8];
#pragma unroll
    for (int jj = 0; jj < 8; ++jj) {
        unsigned short h2[2];
#pragma unroll
        for (int c = 0; c < 2; ++c) {
            int j = jj * 2 + c;
            float p = laneprod;
#pragma unroll
            for (int q = 0; q < 4; ++q) p *= ((j >> q) & 1) ? sq[q] : cq[q];
            h2[c] = __builtin_bit_cast(unsigned short, (_Float16)p);
        }
        buf[jj] = (unsigned int)h2[0] | ((unsigned int)h2[1] << 16);
    }
    uint4* dst = (uint4*)(V + (size_t)b * 1024 + 16 * lane);
    uint4 v0; v0.x = buf[0]; v0.y = buf[1]; v0.z = buf[2]; v0.w = buf[3];
    uint4 v1; v1.x = buf[4]; v1.y = buf[5]; v1.z = buf[6]; v1.w = buf[7];
    dst[0] = v0; dst[1] = v1;
}

// ---------------------------------------------------------------------------
// Kernel A (bench4-verified): blocks [0,256): gates(LDS) + single-column
// transposed basis sim -> Bt rows; blocks [256,...): projection -> V.
// ---------------------------------------------------------------------------
__global__ __launch_bounds__(256) void basis_proj_kernel(
    const float* __restrict__ weights, _Float16* __restrict__ Bt,
    const float* __restrict__ x, const float* __restrict__ Wproj,
    _Float16* __restrict__ V, int B) {
    __shared__ float gmat_s[DEPTH * NQ * 8];
    int tid  = threadIdx.x;
    int lane = tid & 63;
    int w    = tid >> 6;

    if (blockIdx.x < 256) {
        if (tid < DEPTH * NQ) compute_gate(weights, tid, gmat_s + tid * 8);
        __syncthreads();

        int g = blockIdx.x * 4 + w;          // basis index = output row pair
        float ar[16], ai[16];
#pragma unroll
        for (int jj = 0; jj < 16; ++jj) {
            ar[jj] = (lane == (g >> 4) && jj == (g & 15)) ? 1.f : 0.f;
            ai[jj] = 0.f;
        }
        run_circuit_T(ar, ai, gmat_s, lane);

        unsigned int bufr[8], bufi[8];
#pragma unroll
        for (int jj = 0; jj < 8; ++jj) {
            unsigned short r0 = __builtin_bit_cast(unsigned short, (_Float16)ar[2*jj]);
            unsigned short r1 = __builtin_bit_cast(unsigned short, (_Float16)ar[2*jj+1]);
            unsigned short i0 = __builtin_bit_cast(unsigned short, (_Float16)ai[2*jj]);
            unsigned short i1 = __builtin_bit_cast(unsigned short, (_Float16)ai[2*jj+1]);
            bufr[jj] = (unsigned int)r0 | ((unsigned int)r1 << 16);
            bufi[jj] = (unsigned int)i0 | ((unsigned int)i1 << 16);
        }
        uint4* dre = (uint4*)((unsigned short*)Bt + (size_t)(2*g)     * 1024 + 16 * lane);
        uint4* dim = (uint4*)((unsigned short*)Bt + (size_t)(2*g + 1) * 1024 + 16 * lane);
        uint4 v;
        v.x = bufr[0]; v.y = bufr[1]; v.z = bufr[2]; v.w = bufr[3]; dre[0] = v;
        v.x = bufr[4]; v.y = bufr[5]; v.z = bufr[6]; v.w = bufr[7]; dre[1] = v;
        v.x = bufi[0]; v.y = bufi[1]; v.z = bufi[2]; v.w = bufi[3]; dim[0] = v;
        v.x = bufi[4]; v.y = bufi[5]; v.z = bufi[6]; v.w = bufi[7]; dim[1] = v;
    } else {
        int b = (blockIdx.x - 256) * 4 + w;
        if (b < B) proj_v_body(x, Wproj, V, b, lane);
    }
}

// ---------------------------------------------------------------------------
// Kernel B (round 8): 128x256 tile, BK=32, FULL K per block (no K split —
// accumulation chain bitwise-identical to bench4). LDS = 2 x 24 KiB = 48 KiB
// -> 2 blocks/CU co-resident (cross-block TLP hides the per-tile vmcnt(0)
// drain + barrier). 512 threads, 8 waves = 2 wm x 4 wn, wave tile 64x64,
// acc[4][4]. One phase per K-tile: 16 MFMA, 1 barrier (vs 4 before).
// Staging swizzle (scg/csw) identical to the verified scheme.
// Zpart format (B,16,8) unchanged -> combine_head unchanged.
// ---------------------------------------------------------------------------
#define STG(dstA_, dstB_, kt_) do {                                                 \
    async_load16(Abase + (size_t)srow * 1024 + (kt_) * 32 + scg * 8,                \
                 dstA_ + w * 512);                                                  \
    _Pragma("unroll")                                                               \
    for (int s_ = 0; s_ < 2; ++s_) {                                                \
        async_load16(Bbase + (size_t)(s_ * 128 + srow) * 1024 + (kt_) * 32 + scg * 8,\
                     dstB_ + s_ * 4096 + w * 512);                                  \
    }                                                                               \
} while (0)

__global__ __launch_bounds__(512, 4) void gemm_fused_kernel(
    const unsigned short* __restrict__ A,    // V (B,1024)
    const unsigned short* __restrict__ Bt,   // (2048,1024)
    float* __restrict__ Zpart) {             // (B,16,8)
    __shared__ __align__(16) unsigned short lds_s[2 * 12288];  // 48 KiB: 2 x (A 8K + B 16K bytes)
    int tid  = threadIdx.x;
    int lane = tid & 63;
    int w    = tid >> 6;                 // 0..7
    int wm   = w >> 2;                   // 0..1 : 64-row half
    int wn   = w & 3;                    // 0..3 : 64-col quarter
    int by   = blockIdx.x & 7;           // XCD id -> Bt panel (L2 locality)
    int bx   = blockIdx.x >> 3;
    int m0   = bx * 128;
    int n0   = by * 256;
    int quad = lane >> 4;
    int lrow = lane & 15;
    int csw  = (quad ^ ((lrow >> 1) & 3)) * 8;   // swizzled read-chunk offset (shorts)
    int srow = tid >> 2;                          // staging row 0..127
    int scg  = (tid & 3) ^ ((srow >> 1) & 3);     // swizzled source chunk
    const unsigned short* Abase = A  + (size_t)m0 * 1024;
    const unsigned short* Bbase = Bt + (size_t)n0 * 1024;

    f32x4 acc[4][4];
#pragma unroll
    for (int mi = 0; mi < 4; ++mi)
#pragma unroll
        for (int ni = 0; ni < 4; ++ni)
            acc[mi][ni] = (f32x4){0.f, 0.f, 0.f, 0.f};

    // prologue: stage tile 0 into buf 0, drain
    STG(lds_s, lds_s + 4096, 0);
    asm volatile("s_waitcnt vmcnt(0)" ::: "memory");
    __builtin_amdgcn_s_barrier();

    int rowA = wm * 64 + lrow;           // + mi*16 -> 0..127
    int rowB = wn * 64 + lrow;           // + ni*16 -> 0..255

    for (int t = 0; t < 32; ++t) {
        const unsigned short* bufA = lds_s + (t & 1) * 12288;
        const unsigned short* bufB = bufA + 4096;
        unsigned short* nA = lds_s + ((t + 1) & 1) * 12288;
        // stage t+1 early (safe: prev iter's trailing barrier guarantees all
        // waves finished reading the target buffer)
        if (t < 31) STG(nA, nA + 4096, t + 1);
        f16x8 af[4], bf[4];
#pragma unroll
        for (int i = 0; i < 4; ++i)
            af[i] = *(const f16x8*)(bufA + (rowA + i * 16) * 32 + csw);
#pragma unroll
        for (int i = 0; i < 4; ++i)
            bf[i] = *(const f16x8*)(bufB + (rowB + i * 16) * 32 + csw);
        asm volatile("s_waitcnt lgkmcnt(0)" ::: "memory");
        __builtin_amdgcn_sched_barrier(0);
        __builtin_amdgcn_s_setprio(1);
#pragma unroll
        for (int mi = 0; mi < 4; ++mi)
#pragma unroll
            for (int ni = 0; ni < 4; ++ni)
                acc[mi][ni] = __builtin_amdgcn_mfma_f32_16x16x32_f16(
                    af[mi], bf[ni], acc[mi][ni], 0, 0, 0);
        __builtin_amdgcn_s_setprio(0);
        asm volatile("s_waitcnt vmcnt(0)" ::: "memory");   // t+1 staged
        __builtin_amdgcn_s_barrier();                      // all reads of buf[cur] done
    }

    // ---- epilogue: square + signed reduce (stride-9 LDS, conflict-free) ----
    float* Zs = (float*)lds_s;                 // [2 nb][2 half][128 rows][9] = 18 KB
    int nbl  = wn >> 1;
    int half = wn & 1;
#pragma unroll
    for (int mi = 0; mi < 4; ++mi) {
#pragma unroll
        for (int r = 0; r < 4; ++r) {
            float p0 = acc[mi][0][r] * acc[mi][0][r];
            float p1 = acc[mi][1][r] * acc[mi][1][r];
            float p2 = acc[mi][2][r] * acc[mi][2][r];
            float p3 = acc[mi][3][r] * acc[mi][3][r];
            float t0 = (p0 + p1) + (p2 + p3);
            float t3 = (p0 - p1) + (p2 - p3);
            float t4 = (p0 + p1) - (p2 + p3);
            t0 += lane_xor<1>(t0);
            t3 += lane_xor<1>(t3);
            t4 += lane_xor<1>(t4);
            float u2 = lane_xor<2>(t0);
            float ap = t0 + u2;
            float am = (lane & 2) ? u2 - t0 : t0 - u2;
            t3 += lane_xor<2>(t3);
            t4 += lane_xor<2>(t4);
            float u4  = lane_xor<4>(ap);
            float bpp = ap + u4;
            float bpm = (lane & 4) ? u4 - ap : ap - u4;
            float bmp = am + lane_xor<4>(am);
            t3 += lane_xor<4>(t3);
            t4 += lane_xor<4>(t4);
            float u8 = lane_xor<8>(bpp);
            float T  = bpp + u8;
            float Z2 = (lane & 8) ? u8 - bpp : bpp - u8;
            float Z1 = bpm + lane_xor<8>(bpm);
            float Z0 = bmp + lane_xor<8>(bmp);
            t3 += lane_xor<8>(t3);
            t4 += lane_xor<8>(t4);
            if (lrow == 0) {
                int row = wm * 64 + mi * 16 + quad * 4 + r;
                float* z = Zs + ((size_t)(nbl * 2 + half) * 128 + row) * 9;
                z[0] = T;  z[1] = Z0; z[2] = Z1; z[3] = Z2;
                z[4] = t3; z[5] = t4;
            }
        }
    }
    __syncthreads();
    {
        int row  = tid >> 2;                  // 0..127
        int nb   = (tid >> 1) & 1;            // 0..1
        int part = tid & 1;                   // 0..1  (128*2*2 = 512 threads)
        const float* za = Zs + ((size_t)(nb * 2 + 0) * 128 + row) * 9;
        const float* zb = Zs + ((size_t)(nb * 2 + 1) * 128 + row) * 9;
        float o[4];
        if (part == 0) {
            o[0] = za[0] + zb[0];            // T
            o[1] = za[1] + zb[1];            // Z0
            o[2] = za[2] + zb[2];            // Z1
            o[3] = za[3] + zb[3];            // Z2
        } else {
            o[0] = za[4] + zb[4];            // Z3
            o[1] = za[5] + zb[5];            // Z4
            o[2] = za[0] - zb[0];            // Z5
            o[3] = 0.f;
        }
        float4 v = {o[0], o[1], o[2], o[3]};
        *(float4*)(Zpart + ((size_t)(m0 + row) * 16 + (by * 2 + nb)) * 8 + part * 4) = v;
    }
}

// ---------------------------------------------------------------------------
// Kernel C: combine 16 n-tile partials -> Z_q -> output head (bench4-verified).
// ---------------------------------------------------------------------------
__global__ __launch_bounds__(256) void combine_head_kernel(
    const float* __restrict__ Zpart, const float* __restrict__ Wout,
    const float* __restrict__ bout, float* __restrict__ out, int B) {
    int lane = threadIdx.x & 63;
    int wid  = threadIdx.x >> 6;
    int b    = blockIdx.x * 4 + wid;
    if (b >= B) return;

    float z[8];
    if (lane < 16) {
        const float4* p = (const float4*)(Zpart + ((size_t)b * 16 + lane) * 8);
        float4 a = p[0], c = p[1];
        z[0]=a.x; z[1]=a.y; z[2]=a.z; z[3]=a.w; z[4]=c.x; z[5]=c.y; z[6]=c.z; z[7]=c.w;
    } else {
#pragma unroll
        for (int i = 0; i < 8; ++i) z[i] = 0.f;
    }
    float Zq[NQ];
#pragma unroll
    for (int q = 0; q < 6; ++q) {
        float v = z[q + 1];
        v += lane_xor<1>(v);
        v += lane_xor<2>(v);
        v += lane_xor<4>(v);
        v += lane_xor<8>(v);
        Zq[q] = v;
    }
    {
        float T = z[0];
        float u1 = lane_xor<1>(T);
        float P  = T + u1;
        float M  = (lane & 1) ? u1 - T : T - u1;
        float u2 = lane_xor<2>(P);
        float PP = P + u2;
        float PM = (lane & 2) ? u2 - P : P - u2;
        float MP = M + lane_xor<2>(M);
        float u4  = lane_xor<4>(PP);
        float PPP = PP + u4;
        float PPM = (lane & 4) ? u4 - PP : PP - u4;
        float PMP = PM + lane_xor<4>(PM);
        float MPP = MP + lane_xor<4>(MP);
        float u8 = lane_xor<8>(PPP);
        Zq[9] = (lane & 8) ? u8 - PPP : PPP - u8;
        Zq[8] = PPM + lane_xor<8>(PPM);
        Zq[7] = PMP + lane_xor<8>(PMP);
        Zq[6] = MPP + lane_xor<8>(MPP);
    }
    if (lane < NQ) {
        float o = bout[lane];
#pragma unroll
        for (int q = 0; q < NQ; ++q) o = fmaf(Zq[q], Wout[lane * NQ + q], o);
        out[(size_t)b * NQ + lane] = o;
    }
}

// ---------------------------------------------------------------------------
// Fallback: round-1 monolithic kernel (verified).
// ---------------------------------------------------------------------------
__global__ __launch_bounds__(256) void vqc_kernel(
    const float* __restrict__ x, const float* __restrict__ Wproj,
    const float* __restrict__ gmat, const float* __restrict__ Wout,
    const float* __restrict__ bout, float* __restrict__ out, int B) {
    int lane = threadIdx.x & 63;
    int wid  = threadIdx.x >> 6;
    int b    = blockIdx.x * 4 + wid;
    if (b >= B) return;

    const float* xb = x + (size_t)b * 1024;
    float acc[NQ];
#pragma unroll
    for (int q = 0; q < NQ; ++q) acc[q] = 0.f;
#pragma unroll
    for (int k = 0; k < 16; ++k) {
        float xv = xb[k * 64 + lane];
#pragma unroll
        for (int q = 0; q < NQ; ++q)
            acc[q] = fmaf(xv, Wproj[q * 1024 + k * 64 + lane], acc[q]);
    }
#pragma unroll
    for (int q = 0; q < NQ; ++q) acc[q] = wave_sum(acc[q]);

    float cq[NQ], sq[NQ];
#pragma unroll
    for (int q = 0; q < NQ; ++q) {
        float ang = tanhf(acc[q]) * 1.57079632679489662f;
        cq[q] = cosf(0.5f * ang);
        sq[q] = sinf(0.5f * ang);
    }
    float laneprod = 1.f;
#pragma unroll
    for (int q = 4; q < NQ; ++q)
        laneprod *= ((lane >> (q - 4)) & 1) ? sq[q] : cq[q];
    float ar[16], ai[16];
#pragma unroll
    for (int j = 0; j < 16; ++j) {
        float p = laneprod;
#pragma unroll
        for (int q = 0; q < 4; ++q) p *= ((j >> q) & 1) ? sq[q] : cq[q];
        ar[j] = p; ai[j] = 0.f;
    }
    run_circuit(ar, ai, gmat, lane);

    float T = 0.f, S[4] = {0.f, 0.f, 0.f, 0.f};
#pragma unroll
    for (int j = 0; j < 16; ++j) {
        float p = ar[j] * ar[j] + ai[j] * ai[j];
        T += p;
#pragma unroll
        for (int q = 0; q < 4; ++q) S[q] += ((j >> q) & 1) ? -p : p;
    }
    float Zq[NQ];
#pragma unroll
    for (int q = 0; q < 4; ++q) Zq[q] = S[q];
#pragma unroll
    for (int q = 4; q < NQ; ++q) Zq[q] = ((lane >> (q - 4)) & 1) ? -T : T;
#pragma unroll
    for (int q = 0; q < NQ; ++q) Zq[q] = wave_sum(Zq[q]);
    if (lane < NQ) {
        float o = bout[lane];
#pragma unroll
        for (int q = 0; q < NQ; ++q) o = fmaf(Zq[q], Wout[lane * NQ + q], o);
        out[(size_t)b * NQ + lane] = o;
    }
}

extern "C" void kernel_launch(void* const* d_in, const int* in_sizes, int n_in,
                              void* d_out, int out_size, void* d_ws, size_t ws_size,
                              hipStream_t stream) {
    const float* x       = (const float*)d_in[0];
    const float* Wproj   = (const float*)d_in[1];
    const float* weights = (const float*)d_in[2];
    const float* Wout    = (const float*)d_in[3];
    const float* bout    = (const float*)d_in[4];
    float* out = (float*)d_out;
    int B = in_sizes[0] / 1024;

    char* ws = (char*)d_ws;
    size_t off_Bt = 4096;
    size_t off_V  = off_Bt + (size_t)2048 * 1024 * 2;
    size_t off_Z  = off_V  + (size_t)B * 1024 * 2;
    size_t need   = off_Z  + (size_t)B * 16 * 8 * 4;

    if (ws_size >= need && (B % 128) == 0) {
        _Float16* Bt = (_Float16*)(ws + off_Bt);
        _Float16* V  = (_Float16*)(ws + off_V);
        float*  Zprt = (float*)(ws + off_Z);

        basis_proj_kernel<<<256 + (B + 3) / 4, 256, 0, stream>>>(weights, Bt, x, Wproj, V, B);
        gemm_fused_kernel<<<(B / 128) * 8, 512, 0, stream>>>(
            (const unsigned short*)V, (const unsigned short*)Bt, Zprt);
        combine_head_kernel<<<(B + 3) / 4, 256, 0, stream>>>(Zprt, Wout, bout, out, B);
    } else {
        float* gmat = (float*)ws;
        prep_gates_kernel<<<1, 64, 0, stream>>>(weights, gmat);
        vqc_kernel<<<(B + 3) / 4, 256, 0, stream>>>(x, Wproj, gmat, Wout, bout, out, B);
    }
}